// Round 11
// baseline (966.672 us; speedup 1.0000x reference)
//
#include <hip/hip_runtime.h>
#include <cstdio>
#include <cmath>

#define NUM_WORDS 2048
#define NUM_CAND 8192
#define HIDDEN 768
#define FEAT 20
#define FFNN_DIM 1000
#define SPAN_DIM 2324
#define TOP_NUM 819
#define MSW 30
#define KP2 1024   // FFNN padded to x32
#define NP 1024    // padded N
#define PNP 3072   // P matrix padded N (3 segments of 1024)

// d_out layout (floats): [scores 8192][top_idx 819][top_starts 819][top_ends 819]
//                        [top_span_emb 819*2324][top_scores 819]
#define OUT_TOPIDX   (NUM_CAND)
#define OUT_TSTART   (NUM_CAND + TOP_NUM)
#define OUT_TEND     (NUM_CAND + 2*TOP_NUM)
#define OUT_TEMB     (NUM_CAND + 3*TOP_NUM)
#define OUT_TSCORE   (NUM_CAND + 3*TOP_NUM + TOP_NUM*SPAN_DIM)

typedef short short8 __attribute__((ext_vector_type(8)));
typedef float f32x4 __attribute__((ext_vector_type(4)));

__device__ __forceinline__ unsigned short bf16_rne(float x) {
    unsigned int u = __float_as_uint(x);
    unsigned int r = u + 0x7FFFu + ((u >> 16) & 1u);
    return (unsigned short)(r >> 16);
}
__device__ __forceinline__ float bf16_to_f(unsigned short h) {
    return __uint_as_float(((unsigned int)h) << 16);
}
// 3-way split: v = s0 + s1 + s2 + r, |r| <= 2^-27 |v|
__device__ __forceinline__ void store_split3(unsigned short* p0, unsigned short* p1,
                                             unsigned short* p2, size_t off, float v) {
    unsigned short h0 = bf16_rne(v);
    float r1 = v - bf16_to_f(h0);
    unsigned short h1 = bf16_rne(r1);
    float r2 = r1 - bf16_to_f(h1);
    p0[off] = h0;
    p1[off] = h1;
    p2[off] = bf16_rne(r2);
}

// ---------------- head scores: doc @ head_w + head_b  -> [2048] ----------------
__global__ void head_kernel(const float* __restrict__ doc, const float* __restrict__ hw,
                            const float* __restrict__ hb, float* __restrict__ out) {
    int wave = threadIdx.x >> 6, lane = threadIdx.x & 63;
    int row = blockIdx.x * 4 + wave;
    if (row >= NUM_WORDS) return;
    float acc = 0.f;
    for (int h = lane; h < HIDDEN; h += 64) acc += doc[row * HIDDEN + h] * hw[h];
    for (int off = 32; off > 0; off >>= 1) acc += __shfl_down(acc, off);
    if (lane == 0) out[row] = acc + hb[0];
}

// ---------------- width prior ffnn: [30,20] -> [30] ----------------
__global__ void width_kernel(const float* __restrict__ x, const float* __restrict__ w1,
                             const float* __restrict__ b1, const float* __restrict__ w2,
                             const float* __restrict__ b2, const float* __restrict__ w3,
                             const float* __restrict__ b3, float* __restrict__ out) {
    __shared__ float xs[FEAT];
    __shared__ float h1s[FFNN_DIM];
    __shared__ float red[256];
    int r = blockIdx.x, t = threadIdx.x;
    if (t < FEAT) xs[t] = x[r * FEAT + t];
    __syncthreads();
    for (int j = t; j < FFNN_DIM; j += 256) {
        float acc = b1[j];
        for (int k = 0; k < FEAT; ++k) acc += xs[k] * w1[k * FFNN_DIM + j];
        h1s[j] = fmaxf(acc, 0.f);
    }
    __syncthreads();
    float partial = 0.f;
    for (int j = t; j < FFNN_DIM; j += 256) {
        float acc = b2[j];
        for (int k = 0; k < FFNN_DIM; ++k) acc += h1s[k] * w2[k * FFNN_DIM + j];
        partial += fmaxf(acc, 0.f) * w3[j];
    }
    red[t] = partial;
    __syncthreads();
    for (int s = 128; s > 0; s >>= 1) { if (t < s) red[t] += red[t + s]; __syncthreads(); }
    if (t == 0) out[r] = red[0] + b3[0];
}

// ---------------- attention weights per span: attn_g [8192][32] ----------------
__global__ void attn_kernel(const float* __restrict__ head_s, const int* __restrict__ starts,
                            const int* __restrict__ ends, float* __restrict__ attn_g) {
    int wave = threadIdx.x >> 6, w = threadIdx.x & 63;
    int c = blockIdx.x * 4 + wave;
    if (c >= NUM_CAND) return;
    int s = starts[c], e = ends[c];
    int wid = e - s;
    float hsv = -INFINITY;
    if (w < MSW && w <= wid) hsv = head_s[s + w];
    float m = hsv;
    for (int off = 32; off > 0; off >>= 1) m = fmaxf(m, __shfl_down(m, off));
    m = __shfl(m, 0);
    float ex = (w < MSW && w <= wid) ? expf(hsv - m) : 0.f;
    float ssum = ex;
    for (int off = 32; off > 0; off >>= 1) ssum += __shfl_down(ssum, off);
    ssum = __shfl(ssum, 0);
    if (w < 32) attn_g[c * 32 + w] = (w < MSW) ? (ex / ssum) : 0.f;
}

// ---------------- doc fp32 -> 3-split bf16 [2048*768] ----------------
__global__ void doc_convert(const float* __restrict__ doc, unsigned short* __restrict__ d0,
                            unsigned short* __restrict__ d1, unsigned short* __restrict__ d2) {
    int i = blockIdx.x * 256 + threadIdx.x;
    if (i < NUM_WORDS * HIDDEN) store_split3(d0, d1, d2, i, doc[i]);
}

// ---------------- weight convert+transpose: w[K][N] -> 3-split [gridDim.y][Kp] ------------
__global__ void convert_wt(const float* __restrict__ w, int K, int N, int Kp,
                           unsigned short* __restrict__ q0, unsigned short* __restrict__ q1,
                           unsigned short* __restrict__ q2) {
    int n = blockIdx.y;
    int k = blockIdx.x * blockDim.x + threadIdx.x;
    if (k >= Kp) return;
    float v = (k < K && n < N) ? w[(size_t)k * N + n] : 0.f;
    store_split3(q0, q1, q2, (size_t)n * Kp + k, v);
}

// ---------------- T_w[wid][1024] = span_width_emb[wid] @ m_w1[1536:1556] ----------------
__global__ void tw_kernel(const float* __restrict__ swe, const float* __restrict__ w1,
                          float* __restrict__ tw) {
    int wid = blockIdx.x, t = threadIdx.x;
    for (int n = t; n < NP; n += 256) {
        float acc = 0.f;
        if (n < FFNN_DIM) {
            for (int f = 0; f < FEAT; ++f)
                acc += swe[wid * FEAT + f] * w1[(size_t)(1536 + f) * FFNN_DIM + n];
        }
        tw[wid * NP + n] = acc;
    }
}

// ---------------- 3-split 6-product MFMA GEMM, fp32 out: P = doc @ [W_s|W_e|W_a] ---------
__global__ __launch_bounds__(256, 2) void gemm6p(
    const unsigned short* __restrict__ A0, const unsigned short* __restrict__ A1,
    const unsigned short* __restrict__ A2,
    const unsigned short* __restrict__ B0, const unsigned short* __restrict__ B1,
    const unsigned short* __restrict__ B2,
    float* __restrict__ C) {
    __shared__ unsigned short As0[128 * 40], As1[128 * 40], As2[128 * 40];
    __shared__ unsigned short Bs0[128 * 40], Bs1[128 * 40], Bs2[128 * 40];
    int t = threadIdx.x;
    int bid = blockIdx.x;
    int bm = (bid & 15) << 7;
    int bn = (bid >> 4) << 7;
    int lane = t & 63, wv = t >> 6;
    int wm = (wv >> 1) * 64, wn = (wv & 1) * 64;
    int lr = lane & 15, qq = lane >> 4;

    f32x4 acc[4][4] = {};

    for (int k0 = 0; k0 < HIDDEN; k0 += 32) {
#pragma unroll
        for (int qi = 0; qi < 2; ++qi) {
            int u = qi * 256 + t;
            int m = u >> 2, blk = u & 3;
            size_t ga = (size_t)(bm + m) * HIDDEN + k0 + blk * 8;
            size_t gb = (size_t)(bn + m) * HIDDEN + k0 + blk * 8;
            uint4 va0 = *(const uint4*)(A0 + ga);
            uint4 va1 = *(const uint4*)(A1 + ga);
            uint4 va2 = *(const uint4*)(A2 + ga);
            uint4 vb0 = *(const uint4*)(B0 + gb);
            uint4 vb1 = *(const uint4*)(B1 + gb);
            uint4 vb2 = *(const uint4*)(B2 + gb);
            int la = m * 40 + blk * 8;
            *(uint4*)&As0[la] = va0;
            *(uint4*)&As1[la] = va1;
            *(uint4*)&As2[la] = va2;
            *(uint4*)&Bs0[la] = vb0;
            *(uint4*)&Bs1[la] = vb1;
            *(uint4*)&Bs2[la] = vb2;
        }
        __syncthreads();
        short8 a0[4], a1[4], a2[4];
#pragma unroll
        for (int i = 0; i < 4; ++i) {
            int ra = (wm + i * 16 + lr) * 40 + qq * 8;
            a0[i] = *(const short8*)&As0[ra];
            a1[i] = *(const short8*)&As1[ra];
            a2[i] = *(const short8*)&As2[ra];
        }
#pragma unroll
        for (int j = 0; j < 4; ++j) {
            int rb = (wn + j * 16 + lr) * 40 + qq * 8;
            short8 b0 = *(const short8*)&Bs0[rb];
            short8 b1 = *(const short8*)&Bs1[rb];
            short8 b2 = *(const short8*)&Bs2[rb];
#pragma unroll
            for (int i = 0; i < 4; ++i) {
                acc[i][j] = __builtin_amdgcn_mfma_f32_16x16x32_bf16(a2[i], b0, acc[i][j], 0, 0, 0);
                acc[i][j] = __builtin_amdgcn_mfma_f32_16x16x32_bf16(a0[i], b2, acc[i][j], 0, 0, 0);
                acc[i][j] = __builtin_amdgcn_mfma_f32_16x16x32_bf16(a1[i], b1, acc[i][j], 0, 0, 0);
                acc[i][j] = __builtin_amdgcn_mfma_f32_16x16x32_bf16(a1[i], b0, acc[i][j], 0, 0, 0);
                acc[i][j] = __builtin_amdgcn_mfma_f32_16x16x32_bf16(a0[i], b1, acc[i][j], 0, 0, 0);
                acc[i][j] = __builtin_amdgcn_mfma_f32_16x16x32_bf16(a0[i], b0, acc[i][j], 0, 0, 0);
            }
        }
        __syncthreads();
    }
#pragma unroll
    for (int i = 0; i < 4; ++i)
#pragma unroll
        for (int j = 0; j < 4; ++j)
#pragma unroll
            for (int r = 0; r < 4; ++r) {
                int m = bm + wm + i * 16 + qq * 4 + r;
                int n = bn + wn + j * 16 + lr;
                C[(size_t)m * PNP + n] = acc[i][j][r];
            }
}

// ---------------- combine: h1[c] = relu(P_s[s] + P_e[e] + sum attn*P_a[s+w] + Tw + b1) ----
__global__ void combine_kernel(const float* __restrict__ P, const float* __restrict__ tw,
                               const float* __restrict__ attn_g, const float* __restrict__ b1,
                               const int* __restrict__ starts, const int* __restrict__ ends,
                               unsigned short* __restrict__ h0, unsigned short* __restrict__ h1,
                               unsigned short* __restrict__ h2) {
    int c = blockIdx.x, t = threadIdx.x;
    int s = starts[c], e = ends[c];
    int wid = e - s;
    __shared__ float at[MSW];
    if (t < MSW) at[t] = attn_g[c * 32 + t];
    __syncthreads();
    const float* Ps = P + (size_t)s * PNP;
    const float* Pe = P + (size_t)e * PNP + 1024;
    const float* Pa = P + (size_t)s * PNP + 2048;
    const float* Tw = tw + (size_t)wid * NP;
    for (int n = t; n < NP; n += 256) {
        if (n < FFNN_DIM) {
            float acc = Ps[n] + Pe[n] + Tw[n] + b1[n];
            for (int w = 0; w <= wid; ++w) acc += at[w] * Pa[(size_t)w * PNP + n];
            store_split3(h0, h1, h2, (size_t)c * NP + n, fmaxf(acc, 0.f));
        } else {
            h0[(size_t)c * NP + n] = 0;
            h1[(size_t)c * NP + n] = 0;
            h2[(size_t)c * NP + n] = 0;
        }
    }
}

// ---------------- 3-split 6-product MFMA GEMM (score fusion) ------------
__global__ __launch_bounds__(256, 2) void gemm6(
    const unsigned short* __restrict__ A0, const unsigned short* __restrict__ A1,
    const unsigned short* __restrict__ A2,
    const unsigned short* __restrict__ B0, const unsigned short* __restrict__ B1,
    const unsigned short* __restrict__ B2,
    const float* __restrict__ bias, int nreal, int Kp,
    const float* __restrict__ w3, float* __restrict__ partials) {
    __shared__ unsigned short As0[128 * 40], As1[128 * 40], As2[128 * 40];
    __shared__ unsigned short Bs0[128 * 40], Bs1[128 * 40], Bs2[128 * 40];
    int t = threadIdx.x;
    int bid = blockIdx.x;
    int sm = bid >> 6, idx = bid & 63;
    int bm = ((sm << 3) + (idx & 7)) << 7;
    int bn = (idx >> 3) << 7;
    int lane = t & 63, wv = t >> 6;
    int wm = (wv >> 1) * 64, wn = (wv & 1) * 64;
    int lr = lane & 15, qq = lane >> 4;

    f32x4 acc[4][4] = {};

    for (int k0 = 0; k0 < Kp; k0 += 32) {
#pragma unroll
        for (int qi = 0; qi < 2; ++qi) {
            int u = qi * 256 + t;
            int m = u >> 2, blk = u & 3;
            size_t ga = (size_t)(bm + m) * Kp + k0 + blk * 8;
            size_t gb = (size_t)(bn + m) * Kp + k0 + blk * 8;
            uint4 va0 = *(const uint4*)(A0 + ga);
            uint4 va1 = *(const uint4*)(A1 + ga);
            uint4 va2 = *(const uint4*)(A2 + ga);
            uint4 vb0 = *(const uint4*)(B0 + gb);
            uint4 vb1 = *(const uint4*)(B1 + gb);
            uint4 vb2 = *(const uint4*)(B2 + gb);
            int la = m * 40 + blk * 8;
            *(uint4*)&As0[la] = va0;
            *(uint4*)&As1[la] = va1;
            *(uint4*)&As2[la] = va2;
            *(uint4*)&Bs0[la] = vb0;
            *(uint4*)&Bs1[la] = vb1;
            *(uint4*)&Bs2[la] = vb2;
        }
        __syncthreads();
        short8 a0[4], a1[4], a2[4];
#pragma unroll
        for (int i = 0; i < 4; ++i) {
            int ra = (wm + i * 16 + lr) * 40 + qq * 8;
            a0[i] = *(const short8*)&As0[ra];
            a1[i] = *(const short8*)&As1[ra];
            a2[i] = *(const short8*)&As2[ra];
        }
#pragma unroll
        for (int j = 0; j < 4; ++j) {
            int rb = (wn + j * 16 + lr) * 40 + qq * 8;
            short8 b0 = *(const short8*)&Bs0[rb];
            short8 b1 = *(const short8*)&Bs1[rb];
            short8 b2 = *(const short8*)&Bs2[rb];
#pragma unroll
            for (int i = 0; i < 4; ++i) {
                acc[i][j] = __builtin_amdgcn_mfma_f32_16x16x32_bf16(a2[i], b0, acc[i][j], 0, 0, 0);
                acc[i][j] = __builtin_amdgcn_mfma_f32_16x16x32_bf16(a0[i], b2, acc[i][j], 0, 0, 0);
                acc[i][j] = __builtin_amdgcn_mfma_f32_16x16x32_bf16(a1[i], b1, acc[i][j], 0, 0, 0);
                acc[i][j] = __builtin_amdgcn_mfma_f32_16x16x32_bf16(a1[i], b0, acc[i][j], 0, 0, 0);
                acc[i][j] = __builtin_amdgcn_mfma_f32_16x16x32_bf16(a0[i], b1, acc[i][j], 0, 0, 0);
                acc[i][j] = __builtin_amdgcn_mfma_f32_16x16x32_bf16(a0[i], b0, acc[i][j], 0, 0, 0);
            }
        }
        __syncthreads();
    }

    int pid = ((bn >> 7) << 1) | (wn >> 6);  // 0..15
#pragma unroll
    for (int i = 0; i < 4; ++i)
#pragma unroll
        for (int r = 0; r < 4; ++r) {
            float p = 0.f;
#pragma unroll
            for (int j = 0; j < 4; ++j) {
                int n = bn + wn + j * 16 + lr;
                float v = acc[i][j][r] + (n < nreal ? bias[n] : 0.f);
                v = fmaxf(v, 0.f);
                p += v * (n < nreal ? w3[n] : 0.f);
            }
            p += __shfl_xor(p, 1);
            p += __shfl_xor(p, 2);
            p += __shfl_xor(p, 4);
            p += __shfl_xor(p, 8);
            if (lr == 0) {
                int m = bm + wm + i * 16 + qq * 4 + r;
                partials[(size_t)m * 16 + pid] = p;
            }
        }
}

// ---------------- deterministic score finalize ----------------
__global__ void score_final(const float* __restrict__ partials, const float* __restrict__ b3,
                            const float* __restrict__ width_s, const int* __restrict__ starts,
                            const int* __restrict__ ends, float* __restrict__ out) {
    int c = blockIdx.x * 256 + threadIdx.x;
    if (c >= NUM_CAND) return;
    float s = b3[0] + width_s[ends[c] - starts[c]];
#pragma unroll
    for (int p = 0; p < 16; ++p) s += partials[(size_t)c * 16 + p];
    out[c] = s;
}

// ---------------- exact counting rank-sort: 256 blocks ----------------
__global__ __launch_bounds__(256) void rank_kernel(const float* __restrict__ scores,
                                                   const int* __restrict__ starts,
                                                   const int* __restrict__ ends,
                                                   unsigned short* __restrict__ ord_g,
                                                   unsigned int* __restrict__ se_g) {
    __shared__ unsigned long long kk[NUM_CAND];  // 64 KB
    int t = threadIdx.x;
    for (int i = t; i < NUM_CAND; i += 256) {
        unsigned int b = __float_as_uint(scores[i]);
        unsigned int u = b ^ ((b & 0x80000000u) ? 0xFFFFFFFFu : 0x80000000u);
        unsigned int hi = ~u;
        kk[i] = ((unsigned long long)hi << 32) | (unsigned int)i;
    }
    __syncthreads();
    int c = blockIdx.x * 32 + (t >> 3);
    int seg = (t & 7) * 1024;
    unsigned long long mykey = kk[c];
    int cnt = 0;
    for (int i = seg; i < seg + 1024; ++i) cnt += (kk[i] < mykey) ? 1 : 0;
    cnt += __shfl_xor(cnt, 1);
    cnt += __shfl_xor(cnt, 2);
    cnt += __shfl_xor(cnt, 4);
    if ((t & 7) == 0) {
        int idx = (int)(mykey & 0xFFFFFFFFull);
        int rank = cnt;
        ord_g[rank] = (unsigned short)idx;
        se_g[rank] = ((unsigned int)starts[idx] << 16) | (unsigned int)ends[idx];
    }
}

// ---------------- NMS only: 128-candidate chunks (2 per lane), sel ranks -> global --------
// Split from the old select_kernel for rocprof attribution. Lo half (ranks i..i+63) and hi
// half (i+64..i+127) both eval vs chunk-start state; lo accepts patch hi via the closed-form
// register fix-up (all lo < all hi in rank). Accepts buffered in 2 register slots/lane,
// flushed per chunk (r9-verified deferral). NMS decision logic unchanged (verified 7x).
__global__ __launch_bounds__(256) void select_nms(const unsigned int* __restrict__ se_g,
                                                  unsigned short* __restrict__ sel_g,
                                                  int* __restrict__ count_g) {
    __shared__ unsigned int se_arr[NUM_CAND];      // 32 KB
    __shared__ unsigned int st[2 * NUM_WORDS];     // 16 KB: st[2j]=max_end+1, st[2j+1]=min_start
    int t = threadIdx.x;
    for (int i = t; i < NUM_CAND; i += 256) se_arr[i] = se_g[i];
    for (int i = t; i < 2 * NUM_WORDS; i += 256)
        st[i] = (i & 1) ? (unsigned int)NUM_WORDS : 0u;
    __syncthreads();
    if (t >= 64) return;

    const unsigned long long* stp = (const unsigned long long*)st;
    int count = 0;
    for (int i = 0; i < NUM_CAND && count < TOP_NUM; i += 128) {
        unsigned int sev0 = se_arr[i + t];
        unsigned int sev1 = se_arr[i + 64 + t];
        int s0 = (int)(sev0 >> 16), e0 = (int)(sev0 & 0xFFFFu);
        int s1 = (int)(sev1 >> 16), e1 = (int)(sev1 & 0xFFFFu);
        const unsigned long long* bp0 = stp + s0;
        const unsigned long long* bp1 = stp + s1;
        unsigned long long v0[MSW], v1[MSW];
#pragma unroll
        for (int w = 0; w < MSW; ++w) v0[w] = bp0[w];
#pragma unroll
        for (int w = 0; w < MSW; ++w) v1[w] = bp1[w];
        __builtin_amdgcn_sched_group_barrier(0x0100, 62, 0);
        int me0 = (int)(unsigned int)v0[0] - 1;
        bool crossed0 = (s0 < e0) && ((int)(unsigned int)(v0[0] >> 32) < s0);
        int me1 = (int)(unsigned int)v1[0] - 1;
        bool crossed1 = (s1 < e1) && ((int)(unsigned int)(v1[0] >> 32) < s1);
#pragma unroll
        for (int w = 1; w < MSW; ++w) {
            int j0 = s0 + w;
            bool in0 = (j0 <= e0);
            int mej0 = (int)(unsigned int)v0[w] - 1;
            int msj0 = (int)(unsigned int)(v0[w] >> 32);
            crossed0 = crossed0 || (in0 && ((mej0 > e0) || ((j0 < e0) && (msj0 < s0))));
            int j1 = s1 + w;
            bool in1 = (j1 <= e1);
            int mej1 = (int)(unsigned int)v1[w] - 1;
            int msj1 = (int)(unsigned int)(v1[w] >> 32);
            crossed1 = crossed1 || (in1 && ((mej1 > e1) || ((j1 < e1) && (msj1 < s1))));
        }
        bool spec0 = !crossed0 && (me0 != e0);
        bool spec1 = !crossed1 && (me1 != e1);

        unsigned int pendA = 0u, pendB = 0u;
        int rkA = 0, rkB = 0, lcnt = 0;
        bool full = false;

        // lo half
        {
            unsigned long long window = ~0ull;
            while (true) {
                unsigned long long b = __ballot(spec0) & window;
                if (b == 0ull) break;
                int f = __ffsll((unsigned long long)b) - 1;
                unsigned int sef = __builtin_amdgcn_readlane(sev0, (unsigned int)f);
                int sf = (int)(sef >> 16), ef = (int)(sef & 0xFFFFu);
                bool mineA = (t == lcnt), mineB = (t == lcnt - 64);
                pendA = mineA ? sef : pendA;
                rkA = mineA ? (i + f) : rkA;
                pendB = mineB ? sef : pendB;
                rkB = mineB ? (i + f) : rkB;
                lcnt++;
                count++;
                if (count >= TOP_NUM) { full = true; break; }
                window &= (f >= 63) ? 0ull : (~0ull << (f + 1));
                if (t > f) {
                    if (s0 == sf) me0 = max(me0, ef);
                    crossed0 = crossed0 || ((s0 < sf) && (sf <= e0) && (ef > e0))
                                        || ((sf < s0) && (s0 <= ef) && (ef < e0));
                    spec0 = !crossed0 && (me0 != e0);
                }
                // lo accept affects every hi candidate (all hi ranks are later)
                if (s1 == sf) me1 = max(me1, ef);
                crossed1 = crossed1 || ((s1 < sf) && (sf <= e1) && (ef > e1))
                                    || ((sf < s1) && (s1 <= ef) && (ef < e1));
                spec1 = !crossed1 && (me1 != e1);
            }
        }
        // hi half
        if (!full) {
            unsigned long long window = ~0ull;
            while (true) {
                unsigned long long b = __ballot(spec1) & window;
                if (b == 0ull) break;
                int f = __ffsll((unsigned long long)b) - 1;
                unsigned int sef = __builtin_amdgcn_readlane(sev1, (unsigned int)f);
                int sf = (int)(sef >> 16), ef = (int)(sef & 0xFFFFu);
                bool mineA = (t == lcnt), mineB = (t == lcnt - 64);
                pendA = mineA ? sef : pendA;
                rkA = mineA ? (i + 64 + f) : rkA;
                pendB = mineB ? sef : pendB;
                rkB = mineB ? (i + 64 + f) : rkB;
                lcnt++;
                count++;
                if (count >= TOP_NUM) break;
                window &= (f >= 63) ? 0ull : (~0ull << (f + 1));
                if (t > f) {
                    if (s1 == sf) me1 = max(me1, ef);
                    crossed1 = crossed1 || ((s1 < sf) && (sf <= e1) && (ef > e1))
                                        || ((sf < s1) && (s1 <= ef) && (ef < e1));
                    spec1 = !crossed1 && (me1 != e1);
                }
            }
        }
        // flush this chunk's accepts (fire-and-forget; st re-read only at next chunk eval)
        if (t < lcnt) {
            int sf = (int)(pendA >> 16), ef = (int)(pendA & 0xFFFFu);
            sel_g[count - lcnt + t] = (unsigned short)rkA;
            atomicMax(&st[2 * sf], (unsigned int)(ef + 1));
            atomicMin(&st[2 * ef + 1], (unsigned int)sf);
        }
        if (t + 64 < lcnt) {
            int sf = (int)(pendB >> 16), ef = (int)(pendB & 0xFFFFu);
            sel_g[count - lcnt + 64 + t] = (unsigned short)rkB;
            atomicMax(&st[2 * sf], (unsigned int)(ef + 1));
            atomicMin(&st[2 * ef + 1], (unsigned int)sf);
        }
    }
    if (t == 0) *count_g = count;
}

// ---------------- post: final span-order sort + emit ----------------
__global__ __launch_bounds__(256) void select_post(const float* __restrict__ scores,
                                                   const int* __restrict__ starts,
                                                   const int* __restrict__ ends,
                                                   const unsigned short* __restrict__ ord_g,
                                                   const unsigned short* __restrict__ sel_g,
                                                   const int* __restrict__ count_g,
                                                   float* out, int* top_idx_ws) {
    __shared__ unsigned long long fkeys[1024];
    int t = threadIdx.x;
    int count = *count_g;
    for (int i = t; i < 1024; i += 256) {
        unsigned long long k = 0xFFFFFFFFFFFFFFFFull;
        if (i < count) {
            int idx = (int)ord_g[sel_g[i]];
            unsigned int key32 = (unsigned int)(starts[idx] * NUM_WORDS + ends[idx]);
            k = ((unsigned long long)key32 << 32) | (unsigned int)idx;
        }
        fkeys[i] = k;
    }
    __syncthreads();
    for (int size = 2; size <= 1024; size <<= 1) {
        for (int stride = size >> 1; stride > 0; stride >>= 1) {
            for (int i = t; i < 1024; i += 256) {
                int ixj = i ^ stride;
                if (ixj > i) {
                    bool up = ((i & size) == 0);
                    unsigned long long a = fkeys[i], b = fkeys[ixj];
                    if ((a > b) == up) { fkeys[i] = b; fkeys[ixj] = a; }
                }
            }
            __syncthreads();
        }
    }
    for (int i = t; i < TOP_NUM; i += 256) {
        int fi = (i < count) ? (int)(fkeys[i] & 0xFFFFFFFFull)
                             : (int)(fkeys[0] & 0xFFFFFFFFull);
        out[OUT_TOPIDX + i] = (float)fi;
        out[OUT_TSTART + i] = (float)starts[fi];
        out[OUT_TEND + i] = (float)ends[fi];
        out[OUT_TSCORE + i] = scores[fi];
        top_idx_ws[i] = fi;
    }
}

// ---------------- gather top_span_emb rows directly from doc (exact fp32) ----------------
__global__ void gather_emb(const float* __restrict__ doc, const float* __restrict__ swe,
                           const float* __restrict__ attn_g, const int* __restrict__ starts,
                           const int* __restrict__ ends, const int* __restrict__ top_idx_ws,
                           float* __restrict__ out) {
    int r = blockIdx.x, t = threadIdx.x;
    int idx = top_idx_ws[r];
    int s = starts[idx], e = ends[idx];
    int wid = e - s;
    __shared__ float at[MSW];
    if (t < MSW) at[t] = attn_g[(size_t)idx * 32 + t];
    __syncthreads();
    float* dst = out + OUT_TEMB + (size_t)r * SPAN_DIM;
    for (int h = t; h < HIDDEN; h += 256) {
        dst[h] = doc[(size_t)s * HIDDEN + h];
        dst[HIDDEN + h] = doc[(size_t)e * HIDDEN + h];
        float acc = 0.f;
        for (int w = 0; w <= wid; ++w) acc += at[w] * doc[(size_t)(s + w) * HIDDEN + h];
        dst[2 * HIDDEN + FEAT + h] = acc;
    }
    if (t < FEAT) dst[2 * HIDDEN + t] = swe[wid * FEAT + t];
}

extern "C" void kernel_launch(void* const* d_in, const int* in_sizes, int n_in,
                              void* d_out, int out_size, void* d_ws, size_t ws_size,
                              hipStream_t stream) {
    const float* mention_doc = (const float*)d_in[0];
    const float* span_width_emb = (const float*)d_in[1];
    const float* head_w = (const float*)d_in[2];
    const float* head_b = (const float*)d_in[3];
    const float* m_w1 = (const float*)d_in[4];
    const float* m_b1 = (const float*)d_in[5];
    const float* m_w2 = (const float*)d_in[6];
    const float* m_b2 = (const float*)d_in[7];
    const float* m_w3 = (const float*)d_in[8];
    const float* m_b3 = (const float*)d_in[9];
    const float* width_prior_emb = (const float*)d_in[10];
    const float* w_w1 = (const float*)d_in[11];
    const float* w_b1 = (const float*)d_in[12];
    const float* w_w2 = (const float*)d_in[13];
    const float* w_b2 = (const float*)d_in[14];
    const float* w_w3 = (const float*)d_in[15];
    const float* w_b3 = (const float*)d_in[16];
    const int* cand_starts = (const int*)d_in[17];
    const int* cand_ends = (const int*)d_in[18];

    char* w = (char*)d_ws;
    const size_t szH = (size_t)NUM_CAND * NP * 2;
    const size_t szW2 = (size_t)NP * KP2 * 2;
    const size_t szWc = (size_t)PNP * HIDDEN * 2;
    const size_t szD = (size_t)NUM_WORDS * HIDDEN * 2;
    char* p = w;
    unsigned short* h0 = (unsigned short*)p; p += szH;
    unsigned short* h1 = (unsigned short*)p; p += szH;
    unsigned short* h2 = (unsigned short*)p; p += szH;
    unsigned short* w2t0 = (unsigned short*)p; p += szW2;
    unsigned short* w2t1 = (unsigned short*)p; p += szW2;
    unsigned short* w2t2 = (unsigned short*)p; p += szW2;
    unsigned short* Wc0 = (unsigned short*)p; p += szWc;
    unsigned short* Wc1 = (unsigned short*)p; p += szWc;
    unsigned short* Wc2 = (unsigned short*)p; p += szWc;
    unsigned short* d0 = (unsigned short*)p; p += szD;
    unsigned short* d1 = (unsigned short*)p; p += szD;
    unsigned short* d2 = (unsigned short*)p; p += szD;
    float* P = (float*)p; p += (size_t)NUM_WORDS * PNP * 4;
    float* tw = (float*)p; p += (size_t)MSW * NP * 4;
    float* attn_g = (float*)p; p += (size_t)NUM_CAND * 32 * 4;
    float* partials = (float*)p; p += (size_t)NUM_CAND * 16 * 4;
    unsigned short* ord_g = (unsigned short*)p; p += (size_t)NUM_CAND * 2;
    unsigned int* se_g = (unsigned int*)p; p += (size_t)NUM_CAND * 4;
    unsigned short* sel_g = (unsigned short*)p; p += 2048;
    int* count_g = (int*)p; p += 128;
    float* head_s = (float*)p; p += NUM_WORDS * 4;
    float* width_s = (float*)p; p += 128;
    int* top_idx_ws = (int*)p; p += 4096;

    size_t need = (size_t)(p - w);
    if (ws_size < need) {
        fprintf(stderr, "kernel_launch: ws too small (%zu < %zu)\n", ws_size, need);
    }

    float* out = (float*)d_out;

    head_kernel<<<NUM_WORDS / 4, 256, 0, stream>>>(mention_doc, head_w, head_b, head_s);
    width_kernel<<<MSW, 256, 0, stream>>>(width_prior_emb, w_w1, w_b1, w_w2, w_b2, w_w3, w_b3,
                                          width_s);
    attn_kernel<<<NUM_CAND / 4, 256, 0, stream>>>(head_s, cand_starts, cand_ends, attn_g);
    doc_convert<<<(NUM_WORDS * HIDDEN + 255) / 256, 256, 0, stream>>>(mention_doc, d0, d1, d2);
    convert_wt<<<dim3(3, 1024), 256, 0, stream>>>(m_w1, HIDDEN, FFNN_DIM, HIDDEN,
                                                  Wc0, Wc1, Wc2);
    convert_wt<<<dim3(3, 1024), 256, 0, stream>>>(m_w1 + (size_t)HIDDEN * FFNN_DIM, HIDDEN,
                                                  FFNN_DIM, HIDDEN,
                                                  Wc0 + (size_t)1024 * HIDDEN,
                                                  Wc1 + (size_t)1024 * HIDDEN,
                                                  Wc2 + (size_t)1024 * HIDDEN);
    convert_wt<<<dim3(3, 1024), 256, 0, stream>>>(m_w1 + (size_t)1556 * FFNN_DIM, HIDDEN,
                                                  FFNN_DIM, HIDDEN,
                                                  Wc0 + (size_t)2048 * HIDDEN,
                                                  Wc1 + (size_t)2048 * HIDDEN,
                                                  Wc2 + (size_t)2048 * HIDDEN);
    convert_wt<<<dim3(4, 1024), 256, 0, stream>>>(m_w2, FFNN_DIM, FFNN_DIM, KP2,
                                                  w2t0, w2t1, w2t2);
    tw_kernel<<<MSW, 256, 0, stream>>>(span_width_emb, m_w1, tw);
    gemm6p<<<16 * 24, 256, 0, stream>>>(d0, d1, d2, Wc0, Wc1, Wc2, P);
    combine_kernel<<<NUM_CAND, 256, 0, stream>>>(P, tw, attn_g, m_b1, cand_starts, cand_ends,
                                                 h0, h1, h2);
    gemm6<<<512, 256, 0, stream>>>(h0, h1, h2, w2t0, w2t1, w2t2, m_b2, FFNN_DIM, KP2,
                                   m_w3, partials);
    score_final<<<NUM_CAND / 256, 256, 0, stream>>>(partials, m_b3, width_s, cand_starts,
                                                    cand_ends, out);
    rank_kernel<<<NUM_CAND / 32, 256, 0, stream>>>(out, cand_starts, cand_ends, ord_g, se_g);
    select_nms<<<1, 256, 0, stream>>>(se_g, sel_g, count_g);
    select_post<<<1, 256, 0, stream>>>(out, cand_starts, cand_ends, ord_g, sel_g, count_g,
                                       out, top_idx_ws);
    gather_emb<<<TOP_NUM, 256, 0, stream>>>(mention_doc, span_width_emb, attn_g, cand_starts,
                                            cand_ends, top_idx_ws, out);
}

// Round 12
// 945.645 us; speedup vs baseline: 1.0222x; 1.0222x over previous
//
#include <hip/hip_runtime.h>
#include <cstdio>
#include <cmath>

#define NUM_WORDS 2048
#define NUM_CAND 8192
#define HIDDEN 768
#define FEAT 20
#define FFNN_DIM 1000
#define SPAN_DIM 2324
#define TOP_NUM 819
#define MSW 30
#define KP2 1024   // FFNN padded to x32
#define NP 1024    // padded N
#define PNP 3072   // P matrix padded N (3 segments of 1024)

// d_out layout (floats): [scores 8192][top_idx 819][top_starts 819][top_ends 819]
//                        [top_span_emb 819*2324][top_scores 819]
#define OUT_TOPIDX   (NUM_CAND)
#define OUT_TSTART   (NUM_CAND + TOP_NUM)
#define OUT_TEND     (NUM_CAND + 2*TOP_NUM)
#define OUT_TEMB     (NUM_CAND + 3*TOP_NUM)
#define OUT_TSCORE   (NUM_CAND + 3*TOP_NUM + TOP_NUM*SPAN_DIM)

typedef short short8 __attribute__((ext_vector_type(8)));
typedef float f32x4 __attribute__((ext_vector_type(4)));

__device__ __forceinline__ unsigned short bf16_rne(float x) {
    unsigned int u = __float_as_uint(x);
    unsigned int r = u + 0x7FFFu + ((u >> 16) & 1u);
    return (unsigned short)(r >> 16);
}
__device__ __forceinline__ float bf16_to_f(unsigned short h) {
    return __uint_as_float(((unsigned int)h) << 16);
}
// 3-way split: v = s0 + s1 + s2 + r, |r| <= 2^-27 |v|
__device__ __forceinline__ void store_split3(unsigned short* p0, unsigned short* p1,
                                             unsigned short* p2, size_t off, float v) {
    unsigned short h0 = bf16_rne(v);
    float r1 = v - bf16_to_f(h0);
    unsigned short h1 = bf16_rne(r1);
    float r2 = r1 - bf16_to_f(h1);
    p0[off] = h0;
    p1[off] = h1;
    p2[off] = bf16_rne(r2);
}

// async 16B global->LDS (gfx950 global_load_lds_dwordx4). LDS dest must be
// wave-uniform base + lane*16 -> staging tiles are UNPADDED (128x32 bf16, 64B rows),
// bank conflicts handled by XOR swizzle: kblk stored at kblk^(row&3).
__device__ __forceinline__ void gl_lds16(const unsigned short* g, unsigned short* l) {
    __builtin_amdgcn_global_load_lds(
        (const __attribute__((address_space(1))) unsigned short*)g,
        (__attribute__((address_space(3))) unsigned short*)l, 16, 0, 0);
}

// ---------------- head scores: doc @ head_w + head_b  -> [2048] ----------------
__global__ void head_kernel(const float* __restrict__ doc, const float* __restrict__ hw,
                            const float* __restrict__ hb, float* __restrict__ out) {
    int wave = threadIdx.x >> 6, lane = threadIdx.x & 63;
    int row = blockIdx.x * 4 + wave;
    if (row >= NUM_WORDS) return;
    float acc = 0.f;
    for (int h = lane; h < HIDDEN; h += 64) acc += doc[row * HIDDEN + h] * hw[h];
    for (int off = 32; off > 0; off >>= 1) acc += __shfl_down(acc, off);
    if (lane == 0) out[row] = acc + hb[0];
}

// ---------------- width prior ffnn: [30,20] -> [30] ----------------
__global__ void width_kernel(const float* __restrict__ x, const float* __restrict__ w1,
                             const float* __restrict__ b1, const float* __restrict__ w2,
                             const float* __restrict__ b2, const float* __restrict__ w3,
                             const float* __restrict__ b3, float* __restrict__ out) {
    __shared__ float xs[FEAT];
    __shared__ float h1s[FFNN_DIM];
    __shared__ float red[256];
    int r = blockIdx.x, t = threadIdx.x;
    if (t < FEAT) xs[t] = x[r * FEAT + t];
    __syncthreads();
    for (int j = t; j < FFNN_DIM; j += 256) {
        float acc = b1[j];
        for (int k = 0; k < FEAT; ++k) acc += xs[k] * w1[k * FFNN_DIM + j];
        h1s[j] = fmaxf(acc, 0.f);
    }
    __syncthreads();
    float partial = 0.f;
    for (int j = t; j < FFNN_DIM; j += 256) {
        float acc = b2[j];
        for (int k = 0; k < FFNN_DIM; ++k) acc += h1s[k] * w2[k * FFNN_DIM + j];
        partial += fmaxf(acc, 0.f) * w3[j];
    }
    red[t] = partial;
    __syncthreads();
    for (int s = 128; s > 0; s >>= 1) { if (t < s) red[t] += red[t + s]; __syncthreads(); }
    if (t == 0) out[r] = red[0] + b3[0];
}

// ---------------- attention weights per span: attn_g [8192][32] ----------------
__global__ void attn_kernel(const float* __restrict__ head_s, const int* __restrict__ starts,
                            const int* __restrict__ ends, float* __restrict__ attn_g) {
    int wave = threadIdx.x >> 6, w = threadIdx.x & 63;
    int c = blockIdx.x * 4 + wave;
    if (c >= NUM_CAND) return;
    int s = starts[c], e = ends[c];
    int wid = e - s;
    float hsv = -INFINITY;
    if (w < MSW && w <= wid) hsv = head_s[s + w];
    float m = hsv;
    for (int off = 32; off > 0; off >>= 1) m = fmaxf(m, __shfl_down(m, off));
    m = __shfl(m, 0);
    float ex = (w < MSW && w <= wid) ? expf(hsv - m) : 0.f;
    float ssum = ex;
    for (int off = 32; off > 0; off >>= 1) ssum += __shfl_down(ssum, off);
    ssum = __shfl(ssum, 0);
    if (w < 32) attn_g[c * 32 + w] = (w < MSW) ? (ex / ssum) : 0.f;
}

// ---------------- doc fp32 -> 3-split bf16 [2048*768] ----------------
__global__ void doc_convert(const float* __restrict__ doc, unsigned short* __restrict__ d0,
                            unsigned short* __restrict__ d1, unsigned short* __restrict__ d2) {
    int i = blockIdx.x * 256 + threadIdx.x;
    if (i < NUM_WORDS * HIDDEN) store_split3(d0, d1, d2, i, doc[i]);
}

// ---------------- weight convert+transpose: w[K][N] -> 3-split [gridDim.y][Kp] ------------
__global__ void convert_wt(const float* __restrict__ w, int K, int N, int Kp,
                           unsigned short* __restrict__ q0, unsigned short* __restrict__ q1,
                           unsigned short* __restrict__ q2) {
    int n = blockIdx.y;
    int k = blockIdx.x * blockDim.x + threadIdx.x;
    if (k >= Kp) return;
    float v = (k < K && n < N) ? w[(size_t)k * N + n] : 0.f;
    store_split3(q0, q1, q2, (size_t)n * Kp + k, v);
}

// ---------------- T_w[wid][1024] = span_width_emb[wid] @ m_w1[1536:1556] ----------------
__global__ void tw_kernel(const float* __restrict__ swe, const float* __restrict__ w1,
                          float* __restrict__ tw) {
    int wid = blockIdx.x, t = threadIdx.x;
    for (int n = t; n < NP; n += 256) {
        float acc = 0.f;
        if (n < FFNN_DIM) {
            for (int f = 0; f < FEAT; ++f)
                acc += swe[wid * FEAT + f] * w1[(size_t)(1536 + f) * FFNN_DIM + n];
        }
        tw[wid * NP + n] = acc;
    }
}

// Stage one 128x32-bf16 tile (8KB) async into LDS with XOR swizzle.
// u = qi*256+t spans 512 16B-slots; window (u>>6) is wave-uniform; lane slots contiguous.
__device__ __forceinline__ void stage_tile(const unsigned short* __restrict__ src,
                                           unsigned short* lds, int base_row, int Kp, int k0,
                                           int t) {
#pragma unroll
    for (int qi = 0; qi < 2; ++qi) {
        int u = qi * 256 + t;
        int l = u & 63;
        int row = ((u >> 6) << 4) + (l >> 2);
        int cblk = (l & 3) ^ (row & 3);
        const unsigned short* g = src + (size_t)(base_row + row) * Kp + k0 + cblk * 8;
        gl_lds16(g, lds + u * 8);  // u*8 shorts = u*16 bytes
    }
}

// ---------------- 3-split 6-product MFMA GEMM, fp32 out: P = doc @ [W_s|W_e|W_a] ---------
__global__ __launch_bounds__(256, 2) void gemm6p(
    const unsigned short* __restrict__ A0, const unsigned short* __restrict__ A1,
    const unsigned short* __restrict__ A2,
    const unsigned short* __restrict__ B0, const unsigned short* __restrict__ B1,
    const unsigned short* __restrict__ B2,
    float* __restrict__ C) {
    __shared__ unsigned short As0[128 * 32], As1[128 * 32], As2[128 * 32];
    __shared__ unsigned short Bs0[128 * 32], Bs1[128 * 32], Bs2[128 * 32];
    int t = threadIdx.x;
    int bid = blockIdx.x;
    int bm = (bid & 15) << 7;
    int bn = (bid >> 4) << 7;
    int lane = t & 63, wv = t >> 6;
    int wm = (wv >> 1) * 64, wn = (wv & 1) * 64;
    int lr = lane & 15, qq = lane >> 4;
    int sw = (qq ^ (lr & 3)) * 8;  // swizzled k-block offset (shorts)

    f32x4 acc[4][4] = {};

    for (int k0 = 0; k0 < HIDDEN; k0 += 32) {
        stage_tile(A0, As0, bm, HIDDEN, k0, t);
        stage_tile(A1, As1, bm, HIDDEN, k0, t);
        stage_tile(A2, As2, bm, HIDDEN, k0, t);
        stage_tile(B0, Bs0, bn, HIDDEN, k0, t);
        stage_tile(B1, Bs1, bn, HIDDEN, k0, t);
        stage_tile(B2, Bs2, bn, HIDDEN, k0, t);
        __syncthreads();
        short8 a0[4], a1[4], a2[4];
#pragma unroll
        for (int i = 0; i < 4; ++i) {
            int ra = (wm + i * 16 + lr) * 32 + sw;
            a0[i] = *(const short8*)&As0[ra];
            a1[i] = *(const short8*)&As1[ra];
            a2[i] = *(const short8*)&As2[ra];
        }
#pragma unroll
        for (int j = 0; j < 4; ++j) {
            int rb = (wn + j * 16 + lr) * 32 + sw;
            short8 b0 = *(const short8*)&Bs0[rb];
            short8 b1 = *(const short8*)&Bs1[rb];
            short8 b2 = *(const short8*)&Bs2[rb];
#pragma unroll
            for (int i = 0; i < 4; ++i) {
                acc[i][j] = __builtin_amdgcn_mfma_f32_16x16x32_bf16(a2[i], b0, acc[i][j], 0, 0, 0);
                acc[i][j] = __builtin_amdgcn_mfma_f32_16x16x32_bf16(a0[i], b2, acc[i][j], 0, 0, 0);
                acc[i][j] = __builtin_amdgcn_mfma_f32_16x16x32_bf16(a1[i], b1, acc[i][j], 0, 0, 0);
                acc[i][j] = __builtin_amdgcn_mfma_f32_16x16x32_bf16(a1[i], b0, acc[i][j], 0, 0, 0);
                acc[i][j] = __builtin_amdgcn_mfma_f32_16x16x32_bf16(a0[i], b1, acc[i][j], 0, 0, 0);
                acc[i][j] = __builtin_amdgcn_mfma_f32_16x16x32_bf16(a0[i], b0, acc[i][j], 0, 0, 0);
            }
        }
        __syncthreads();
    }
#pragma unroll
    for (int i = 0; i < 4; ++i)
#pragma unroll
        for (int j = 0; j < 4; ++j)
#pragma unroll
            for (int r = 0; r < 4; ++r) {
                int m = bm + wm + i * 16 + qq * 4 + r;
                int n = bn + wn + j * 16 + lr;
                C[(size_t)m * PNP + n] = acc[i][j][r];
            }
}

// ---------------- combine: h1[c] = relu(P_s[s] + P_e[e] + sum attn*P_a[s+w] + Tw + b1) ----
__global__ void combine_kernel(const float* __restrict__ P, const float* __restrict__ tw,
                               const float* __restrict__ attn_g, const float* __restrict__ b1,
                               const int* __restrict__ starts, const int* __restrict__ ends,
                               unsigned short* __restrict__ h0, unsigned short* __restrict__ h1,
                               unsigned short* __restrict__ h2) {
    int c = blockIdx.x, t = threadIdx.x;
    int s = starts[c], e = ends[c];
    int wid = e - s;
    __shared__ float at[MSW];
    if (t < MSW) at[t] = attn_g[c * 32 + t];
    __syncthreads();
    const float* Ps = P + (size_t)s * PNP;
    const float* Pe = P + (size_t)e * PNP + 1024;
    const float* Pa = P + (size_t)s * PNP + 2048;
    const float* Tw = tw + (size_t)wid * NP;
    for (int n = t; n < NP; n += 256) {
        if (n < FFNN_DIM) {
            float acc = Ps[n] + Pe[n] + Tw[n] + b1[n];
            for (int w = 0; w <= wid; ++w) acc += at[w] * Pa[(size_t)w * PNP + n];
            store_split3(h0, h1, h2, (size_t)c * NP + n, fmaxf(acc, 0.f));
        } else {
            h0[(size_t)c * NP + n] = 0;
            h1[(size_t)c * NP + n] = 0;
            h2[(size_t)c * NP + n] = 0;
        }
    }
}

// ---------------- 3-split 6-product MFMA GEMM (score fusion) ------------
__global__ __launch_bounds__(256, 2) void gemm6(
    const unsigned short* __restrict__ A0, const unsigned short* __restrict__ A1,
    const unsigned short* __restrict__ A2,
    const unsigned short* __restrict__ B0, const unsigned short* __restrict__ B1,
    const unsigned short* __restrict__ B2,
    const float* __restrict__ bias, int nreal, int Kp,
    const float* __restrict__ w3, float* __restrict__ partials) {
    __shared__ unsigned short As0[128 * 32], As1[128 * 32], As2[128 * 32];
    __shared__ unsigned short Bs0[128 * 32], Bs1[128 * 32], Bs2[128 * 32];
    int t = threadIdx.x;
    int bid = blockIdx.x;
    int sm = bid >> 6, idx = bid & 63;
    int bm = ((sm << 3) + (idx & 7)) << 7;
    int bn = (idx >> 3) << 7;
    int lane = t & 63, wv = t >> 6;
    int wm = (wv >> 1) * 64, wn = (wv & 1) * 64;
    int lr = lane & 15, qq = lane >> 4;
    int sw = (qq ^ (lr & 3)) * 8;

    f32x4 acc[4][4] = {};

    for (int k0 = 0; k0 < Kp; k0 += 32) {
        stage_tile(A0, As0, bm, Kp, k0, t);
        stage_tile(A1, As1, bm, Kp, k0, t);
        stage_tile(A2, As2, bm, Kp, k0, t);
        stage_tile(B0, Bs0, bn, Kp, k0, t);
        stage_tile(B1, Bs1, bn, Kp, k0, t);
        stage_tile(B2, Bs2, bn, Kp, k0, t);
        __syncthreads();
        short8 a0[4], a1[4], a2[4];
#pragma unroll
        for (int i = 0; i < 4; ++i) {
            int ra = (wm + i * 16 + lr) * 32 + sw;
            a0[i] = *(const short8*)&As0[ra];
            a1[i] = *(const short8*)&As1[ra];
            a2[i] = *(const short8*)&As2[ra];
        }
#pragma unroll
        for (int j = 0; j < 4; ++j) {
            int rb = (wn + j * 16 + lr) * 32 + sw;
            short8 b0 = *(const short8*)&Bs0[rb];
            short8 b1 = *(const short8*)&Bs1[rb];
            short8 b2 = *(const short8*)&Bs2[rb];
#pragma unroll
            for (int i = 0; i < 4; ++i) {
                acc[i][j] = __builtin_amdgcn_mfma_f32_16x16x32_bf16(a2[i], b0, acc[i][j], 0, 0, 0);
                acc[i][j] = __builtin_amdgcn_mfma_f32_16x16x32_bf16(a0[i], b2, acc[i][j], 0, 0, 0);
                acc[i][j] = __builtin_amdgcn_mfma_f32_16x16x32_bf16(a1[i], b1, acc[i][j], 0, 0, 0);
                acc[i][j] = __builtin_amdgcn_mfma_f32_16x16x32_bf16(a1[i], b0, acc[i][j], 0, 0, 0);
                acc[i][j] = __builtin_amdgcn_mfma_f32_16x16x32_bf16(a0[i], b1, acc[i][j], 0, 0, 0);
                acc[i][j] = __builtin_amdgcn_mfma_f32_16x16x32_bf16(a0[i], b0, acc[i][j], 0, 0, 0);
            }
        }
        __syncthreads();
    }

    int pid = ((bn >> 7) << 1) | (wn >> 6);  // 0..15
#pragma unroll
    for (int i = 0; i < 4; ++i)
#pragma unroll
        for (int r = 0; r < 4; ++r) {
            float p = 0.f;
#pragma unroll
            for (int j = 0; j < 4; ++j) {
                int n = bn + wn + j * 16 + lr;
                float v = acc[i][j][r] + (n < nreal ? bias[n] : 0.f);
                v = fmaxf(v, 0.f);
                p += v * (n < nreal ? w3[n] : 0.f);
            }
            p += __shfl_xor(p, 1);
            p += __shfl_xor(p, 2);
            p += __shfl_xor(p, 4);
            p += __shfl_xor(p, 8);
            if (lr == 0) {
                int m = bm + wm + i * 16 + qq * 4 + r;
                partials[(size_t)m * 16 + pid] = p;
            }
        }
}

// ---------------- deterministic score finalize ----------------
__global__ void score_final(const float* __restrict__ partials, const float* __restrict__ b3,
                            const float* __restrict__ width_s, const int* __restrict__ starts,
                            const int* __restrict__ ends, float* __restrict__ out) {
    int c = blockIdx.x * 256 + threadIdx.x;
    if (c >= NUM_CAND) return;
    float s = b3[0] + width_s[ends[c] - starts[c]];
#pragma unroll
    for (int p = 0; p < 16; ++p) s += partials[(size_t)c * 16 + p];
    out[c] = s;
}

// ---------------- exact counting rank-sort: 256 blocks ----------------
__global__ __launch_bounds__(256) void rank_kernel(const float* __restrict__ scores,
                                                   const int* __restrict__ starts,
                                                   const int* __restrict__ ends,
                                                   unsigned short* __restrict__ ord_g,
                                                   unsigned int* __restrict__ se_g) {
    __shared__ unsigned long long kk[NUM_CAND];  // 64 KB
    int t = threadIdx.x;
    for (int i = t; i < NUM_CAND; i += 256) {
        unsigned int b = __float_as_uint(scores[i]);
        unsigned int u = b ^ ((b & 0x80000000u) ? 0xFFFFFFFFu : 0x80000000u);
        unsigned int hi = ~u;
        kk[i] = ((unsigned long long)hi << 32) | (unsigned int)i;
    }
    __syncthreads();
    int c = blockIdx.x * 32 + (t >> 3);
    int seg = (t & 7) * 1024;
    unsigned long long mykey = kk[c];
    int cnt = 0;
    for (int i = seg; i < seg + 1024; ++i) cnt += (kk[i] < mykey) ? 1 : 0;
    cnt += __shfl_xor(cnt, 1);
    cnt += __shfl_xor(cnt, 2);
    cnt += __shfl_xor(cnt, 4);
    if ((t & 7) == 0) {
        int idx = (int)(mykey & 0xFFFFFFFFull);
        int rank = cnt;
        ord_g[rank] = (unsigned short)idx;
        se_g[rank] = ((unsigned int)starts[idx] << 16) | (unsigned int)ends[idx];
    }
}

// ---------------- NMS (r11 form — single-wave latency floor, parked) ----------------
__global__ __launch_bounds__(256) void select_nms(const unsigned int* __restrict__ se_g,
                                                  unsigned short* __restrict__ sel_g,
                                                  int* __restrict__ count_g) {
    __shared__ unsigned int se_arr[NUM_CAND];
    __shared__ unsigned int st[2 * NUM_WORDS];
    int t = threadIdx.x;
    for (int i = t; i < NUM_CAND; i += 256) se_arr[i] = se_g[i];
    for (int i = t; i < 2 * NUM_WORDS; i += 256)
        st[i] = (i & 1) ? (unsigned int)NUM_WORDS : 0u;
    __syncthreads();
    if (t >= 64) return;

    const unsigned long long* stp = (const unsigned long long*)st;
    int count = 0;
    for (int i = 0; i < NUM_CAND && count < TOP_NUM; i += 128) {
        unsigned int sev0 = se_arr[i + t];
        unsigned int sev1 = se_arr[i + 64 + t];
        int s0 = (int)(sev0 >> 16), e0 = (int)(sev0 & 0xFFFFu);
        int s1 = (int)(sev1 >> 16), e1 = (int)(sev1 & 0xFFFFu);
        const unsigned long long* bp0 = stp + s0;
        const unsigned long long* bp1 = stp + s1;
        unsigned long long v0[MSW], v1[MSW];
#pragma unroll
        for (int w = 0; w < MSW; ++w) v0[w] = bp0[w];
#pragma unroll
        for (int w = 0; w < MSW; ++w) v1[w] = bp1[w];
        __builtin_amdgcn_sched_group_barrier(0x0100, 62, 0);
        int me0 = (int)(unsigned int)v0[0] - 1;
        bool crossed0 = (s0 < e0) && ((int)(unsigned int)(v0[0] >> 32) < s0);
        int me1 = (int)(unsigned int)v1[0] - 1;
        bool crossed1 = (s1 < e1) && ((int)(unsigned int)(v1[0] >> 32) < s1);
#pragma unroll
        for (int w = 1; w < MSW; ++w) {
            int j0 = s0 + w;
            bool in0 = (j0 <= e0);
            int mej0 = (int)(unsigned int)v0[w] - 1;
            int msj0 = (int)(unsigned int)(v0[w] >> 32);
            crossed0 = crossed0 || (in0 && ((mej0 > e0) || ((j0 < e0) && (msj0 < s0))));
            int j1 = s1 + w;
            bool in1 = (j1 <= e1);
            int mej1 = (int)(unsigned int)v1[w] - 1;
            int msj1 = (int)(unsigned int)(v1[w] >> 32);
            crossed1 = crossed1 || (in1 && ((mej1 > e1) || ((j1 < e1) && (msj1 < s1))));
        }
        bool spec0 = !crossed0 && (me0 != e0);
        bool spec1 = !crossed1 && (me1 != e1);

        unsigned int pendA = 0u, pendB = 0u;
        int rkA = 0, rkB = 0, lcnt = 0;
        bool full = false;

        {
            unsigned long long window = ~0ull;
            while (true) {
                unsigned long long b = __ballot(spec0) & window;
                if (b == 0ull) break;
                int f = __ffsll((unsigned long long)b) - 1;
                unsigned int sef = __builtin_amdgcn_readlane(sev0, (unsigned int)f);
                int sf = (int)(sef >> 16), ef = (int)(sef & 0xFFFFu);
                bool mineA = (t == lcnt), mineB = (t == lcnt - 64);
                pendA = mineA ? sef : pendA;
                rkA = mineA ? (i + f) : rkA;
                pendB = mineB ? sef : pendB;
                rkB = mineB ? (i + f) : rkB;
                lcnt++;
                count++;
                if (count >= TOP_NUM) { full = true; break; }
                window &= (f >= 63) ? 0ull : (~0ull << (f + 1));
                if (t > f) {
                    if (s0 == sf) me0 = max(me0, ef);
                    crossed0 = crossed0 || ((s0 < sf) && (sf <= e0) && (ef > e0))
                                        || ((sf < s0) && (s0 <= ef) && (ef < e0));
                    spec0 = !crossed0 && (me0 != e0);
                }
                if (s1 == sf) me1 = max(me1, ef);
                crossed1 = crossed1 || ((s1 < sf) && (sf <= e1) && (ef > e1))
                                    || ((sf < s1) && (s1 <= ef) && (ef < e1));
                spec1 = !crossed1 && (me1 != e1);
            }
        }
        if (!full) {
            unsigned long long window = ~0ull;
            while (true) {
                unsigned long long b = __ballot(spec1) & window;
                if (b == 0ull) break;
                int f = __ffsll((unsigned long long)b) - 1;
                unsigned int sef = __builtin_amdgcn_readlane(sev1, (unsigned int)f);
                int sf = (int)(sef >> 16), ef = (int)(sef & 0xFFFFu);
                bool mineA = (t == lcnt), mineB = (t == lcnt - 64);
                pendA = mineA ? sef : pendA;
                rkA = mineA ? (i + 64 + f) : rkA;
                pendB = mineB ? sef : pendB;
                rkB = mineB ? (i + 64 + f) : rkB;
                lcnt++;
                count++;
                if (count >= TOP_NUM) break;
                window &= (f >= 63) ? 0ull : (~0ull << (f + 1));
                if (t > f) {
                    if (s1 == sf) me1 = max(me1, ef);
                    crossed1 = crossed1 || ((s1 < sf) && (sf <= e1) && (ef > e1))
                                        || ((sf < s1) && (s1 <= ef) && (ef < e1));
                    spec1 = !crossed1 && (me1 != e1);
                }
            }
        }
        if (t < lcnt) {
            int sf = (int)(pendA >> 16), ef = (int)(pendA & 0xFFFFu);
            sel_g[count - lcnt + t] = (unsigned short)rkA;
            atomicMax(&st[2 * sf], (unsigned int)(ef + 1));
            atomicMin(&st[2 * ef + 1], (unsigned int)sf);
        }
        if (t + 64 < lcnt) {
            int sf = (int)(pendB >> 16), ef = (int)(pendB & 0xFFFFu);
            sel_g[count - lcnt + 64 + t] = (unsigned short)rkB;
            atomicMax(&st[2 * sf], (unsigned int)(ef + 1));
            atomicMin(&st[2 * ef + 1], (unsigned int)sf);
        }
    }
    if (t == 0) *count_g = count;
}

// ---------------- post: final span-order sort + emit ----------------
__global__ __launch_bounds__(256) void select_post(const float* __restrict__ scores,
                                                   const int* __restrict__ starts,
                                                   const int* __restrict__ ends,
                                                   const unsigned short* __restrict__ ord_g,
                                                   const unsigned short* __restrict__ sel_g,
                                                   const int* __restrict__ count_g,
                                                   float* out, int* top_idx_ws) {
    __shared__ unsigned long long fkeys[1024];
    int t = threadIdx.x;
    int count = *count_g;
    for (int i = t; i < 1024; i += 256) {
        unsigned long long k = 0xFFFFFFFFFFFFFFFFull;
        if (i < count) {
            int idx = (int)ord_g[sel_g[i]];
            unsigned int key32 = (unsigned int)(starts[idx] * NUM_WORDS + ends[idx]);
            k = ((unsigned long long)key32 << 32) | (unsigned int)idx;
        }
        fkeys[i] = k;
    }
    __syncthreads();
    for (int size = 2; size <= 1024; size <<= 1) {
        for (int stride = size >> 1; stride > 0; stride >>= 1) {
            for (int i = t; i < 1024; i += 256) {
                int ixj = i ^ stride;
                if (ixj > i) {
                    bool up = ((i & size) == 0);
                    unsigned long long a = fkeys[i], b = fkeys[ixj];
                    if ((a > b) == up) { fkeys[i] = b; fkeys[ixj] = a; }
                }
            }
            __syncthreads();
        }
    }
    for (int i = t; i < TOP_NUM; i += 256) {
        int fi = (i < count) ? (int)(fkeys[i] & 0xFFFFFFFFull)
                             : (int)(fkeys[0] & 0xFFFFFFFFull);
        out[OUT_TOPIDX + i] = (float)fi;
        out[OUT_TSTART + i] = (float)starts[fi];
        out[OUT_TEND + i] = (float)ends[fi];
        out[OUT_TSCORE + i] = scores[fi];
        top_idx_ws[i] = fi;
    }
}

// ---------------- gather top_span_emb rows directly from doc (exact fp32) ----------------
__global__ void gather_emb(const float* __restrict__ doc, const float* __restrict__ swe,
                           const float* __restrict__ attn_g, const int* __restrict__ starts,
                           const int* __restrict__ ends, const int* __restrict__ top_idx_ws,
                           float* __restrict__ out) {
    int r = blockIdx.x, t = threadIdx.x;
    int idx = top_idx_ws[r];
    int s = starts[idx], e = ends[idx];
    int wid = e - s;
    __shared__ float at[MSW];
    if (t < MSW) at[t] = attn_g[(size_t)idx * 32 + t];
    __syncthreads();
    float* dst = out + OUT_TEMB + (size_t)r * SPAN_DIM;
    for (int h = t; h < HIDDEN; h += 256) {
        dst[h] = doc[(size_t)s * HIDDEN + h];
        dst[HIDDEN + h] = doc[(size_t)e * HIDDEN + h];
        float acc = 0.f;
        for (int w = 0; w <= wid; ++w) acc += at[w] * doc[(size_t)(s + w) * HIDDEN + h];
        dst[2 * HIDDEN + FEAT + h] = acc;
    }
    if (t < FEAT) dst[2 * HIDDEN + t] = swe[wid * FEAT + t];
}

extern "C" void kernel_launch(void* const* d_in, const int* in_sizes, int n_in,
                              void* d_out, int out_size, void* d_ws, size_t ws_size,
                              hipStream_t stream) {
    const float* mention_doc = (const float*)d_in[0];
    const float* span_width_emb = (const float*)d_in[1];
    const float* head_w = (const float*)d_in[2];
    const float* head_b = (const float*)d_in[3];
    const float* m_w1 = (const float*)d_in[4];
    const float* m_b1 = (const float*)d_in[5];
    const float* m_w2 = (const float*)d_in[6];
    const float* m_b2 = (const float*)d_in[7];
    const float* m_w3 = (const float*)d_in[8];
    const float* m_b3 = (const float*)d_in[9];
    const float* width_prior_emb = (const float*)d_in[10];
    const float* w_w1 = (const float*)d_in[11];
    const float* w_b1 = (const float*)d_in[12];
    const float* w_w2 = (const float*)d_in[13];
    const float* w_b2 = (const float*)d_in[14];
    const float* w_w3 = (const float*)d_in[15];
    const float* w_b3 = (const float*)d_in[16];
    const int* cand_starts = (const int*)d_in[17];
    const int* cand_ends = (const int*)d_in[18];

    char* w = (char*)d_ws;
    const size_t szH = (size_t)NUM_CAND * NP * 2;
    const size_t szW2 = (size_t)NP * KP2 * 2;
    const size_t szWc = (size_t)PNP * HIDDEN * 2;
    const size_t szD = (size_t)NUM_WORDS * HIDDEN * 2;
    char* p = w;
    unsigned short* h0 = (unsigned short*)p; p += szH;
    unsigned short* h1 = (unsigned short*)p; p += szH;
    unsigned short* h2 = (unsigned short*)p; p += szH;
    unsigned short* w2t0 = (unsigned short*)p; p += szW2;
    unsigned short* w2t1 = (unsigned short*)p; p += szW2;
    unsigned short* w2t2 = (unsigned short*)p; p += szW2;
    unsigned short* Wc0 = (unsigned short*)p; p += szWc;
    unsigned short* Wc1 = (unsigned short*)p; p += szWc;
    unsigned short* Wc2 = (unsigned short*)p; p += szWc;
    unsigned short* d0 = (unsigned short*)p; p += szD;
    unsigned short* d1 = (unsigned short*)p; p += szD;
    unsigned short* d2 = (unsigned short*)p; p += szD;
    float* P = (float*)p; p += (size_t)NUM_WORDS * PNP * 4;
    float* tw = (float*)p; p += (size_t)MSW * NP * 4;
    float* attn_g = (float*)p; p += (size_t)NUM_CAND * 32 * 4;
    float* partials = (float*)p; p += (size_t)NUM_CAND * 16 * 4;
    unsigned short* ord_g = (unsigned short*)p; p += (size_t)NUM_CAND * 2;
    unsigned int* se_g = (unsigned int*)p; p += (size_t)NUM_CAND * 4;
    unsigned short* sel_g = (unsigned short*)p; p += 2048;
    int* count_g = (int*)p; p += 128;
    float* head_s = (float*)p; p += NUM_WORDS * 4;
    float* width_s = (float*)p; p += 128;
    int* top_idx_ws = (int*)p; p += 4096;

    size_t need = (size_t)(p - w);
    if (ws_size < need) {
        fprintf(stderr, "kernel_launch: ws too small (%zu < %zu)\n", ws_size, need);
    }

    float* out = (float*)d_out;

    head_kernel<<<NUM_WORDS / 4, 256, 0, stream>>>(mention_doc, head_w, head_b, head_s);
    width_kernel<<<MSW, 256, 0, stream>>>(width_prior_emb, w_w1, w_b1, w_w2, w_b2, w_w3, w_b3,
                                          width_s);
    attn_kernel<<<NUM_CAND / 4, 256, 0, stream>>>(head_s, cand_starts, cand_ends, attn_g);
    doc_convert<<<(NUM_WORDS * HIDDEN + 255) / 256, 256, 0, stream>>>(mention_doc, d0, d1, d2);
    convert_wt<<<dim3(3, 1024), 256, 0, stream>>>(m_w1, HIDDEN, FFNN_DIM, HIDDEN,
                                                  Wc0, Wc1, Wc2);
    convert_wt<<<dim3(3, 1024), 256, 0, stream>>>(m_w1 + (size_t)HIDDEN * FFNN_DIM, HIDDEN,
                                                  FFNN_DIM, HIDDEN,
                                                  Wc0 + (size_t)1024 * HIDDEN,
                                                  Wc1 + (size_t)1024 * HIDDEN,
                                                  Wc2 + (size_t)1024 * HIDDEN);
    convert_wt<<<dim3(3, 1024), 256, 0, stream>>>(m_w1 + (size_t)1556 * FFNN_DIM, HIDDEN,
                                                  FFNN_DIM, HIDDEN,
                                                  Wc0 + (size_t)2048 * HIDDEN,
                                                  Wc1 + (size_t)2048 * HIDDEN,
                                                  Wc2 + (size_t)2048 * HIDDEN);
    convert_wt<<<dim3(4, 1024), 256, 0, stream>>>(m_w2, FFNN_DIM, FFNN_DIM, KP2,
                                                  w2t0, w2t1, w2t2);
    tw_kernel<<<MSW, 256, 0, stream>>>(span_width_emb, m_w1, tw);
    gemm6p<<<16 * 24, 256, 0, stream>>>(d0, d1, d2, Wc0, Wc1, Wc2, P);
    combine_kernel<<<NUM_CAND, 256, 0, stream>>>(P, tw, attn_g, m_b1, cand_starts, cand_ends,
                                                 h0, h1, h2);
    gemm6<<<512, 256, 0, stream>>>(h0, h1, h2, w2t0, w2t1, w2t2, m_b2, FFNN_DIM, KP2,
                                   m_w3, partials);
    score_final<<<NUM_CAND / 256, 256, 0, stream>>>(partials, m_b3, width_s, cand_starts,
                                                    cand_ends, out);
    rank_kernel<<<NUM_CAND / 32, 256, 0, stream>>>(out, cand_starts, cand_ends, ord_g, se_g);
    select_nms<<<1, 256, 0, stream>>>(se_g, sel_g, count_g);
    select_post<<<1, 256, 0, stream>>>(out, cand_starts, cand_ends, ord_g, sel_g, count_g,
                                       out, top_idx_ws);
    gather_emb<<<TOP_NUM, 256, 0, stream>>>(mention_doc, span_width_emb, attn_g, cand_starts,
                                            cand_ends, top_idx_ws, out);
}

// Round 13
// 901.962 us; speedup vs baseline: 1.0717x; 1.0484x over previous
//
#include <hip/hip_runtime.h>
#include <cstdio>
#include <cmath>

#define NUM_WORDS 2048
#define NUM_CAND 8192
#define HIDDEN 768
#define FEAT 20
#define FFNN_DIM 1000
#define SPAN_DIM 2324
#define TOP_NUM 819
#define MSW 30
#define KP2 1024   // FFNN padded to x32
#define NP 1024    // padded N
#define PNP 3072   // P matrix padded N (3 segments of 1024)

// d_out layout (floats): [scores 8192][top_idx 819][top_starts 819][top_ends 819]
//                        [top_span_emb 819*2324][top_scores 819]
#define OUT_TOPIDX   (NUM_CAND)
#define OUT_TSTART   (NUM_CAND + TOP_NUM)
#define OUT_TEND     (NUM_CAND + 2*TOP_NUM)
#define OUT_TEMB     (NUM_CAND + 3*TOP_NUM)
#define OUT_TSCORE   (NUM_CAND + 3*TOP_NUM + TOP_NUM*SPAN_DIM)

typedef short short8 __attribute__((ext_vector_type(8)));
typedef float f32x4 __attribute__((ext_vector_type(4)));

__device__ __forceinline__ unsigned short bf16_rne(float x) {
    unsigned int u = __float_as_uint(x);
    unsigned int r = u + 0x7FFFu + ((u >> 16) & 1u);
    return (unsigned short)(r >> 16);
}
__device__ __forceinline__ float bf16_to_f(unsigned short h) {
    return __uint_as_float(((unsigned int)h) << 16);
}
// 3-way split: v = s0 + s1 + s2 + r, |r| <= 2^-27 |v|
__device__ __forceinline__ void store_split3(unsigned short* p0, unsigned short* p1,
                                             unsigned short* p2, size_t off, float v) {
    unsigned short h0 = bf16_rne(v);
    float r1 = v - bf16_to_f(h0);
    unsigned short h1 = bf16_rne(r1);
    float r2 = r1 - bf16_to_f(h1);
    p0[off] = h0;
    p1[off] = h1;
    p2[off] = bf16_rne(r2);
}

// async 16B global->LDS (gfx950 global_load_lds_dwordx4). LDS dest must be
// wave-uniform base + lane*16 -> staging tiles are UNPADDED (128x32 bf16, 64B rows),
// bank conflicts handled by XOR swizzle: kblk stored at kblk^(row&3).
__device__ __forceinline__ void gl_lds16(const unsigned short* g, unsigned short* l) {
    __builtin_amdgcn_global_load_lds(
        (const __attribute__((address_space(1))) unsigned short*)g,
        (__attribute__((address_space(3))) unsigned short*)l, 16, 0, 0);
}

// ---------------- head scores: doc @ head_w + head_b  -> [2048] ----------------
__global__ void head_kernel(const float* __restrict__ doc, const float* __restrict__ hw,
                            const float* __restrict__ hb, float* __restrict__ out) {
    int wave = threadIdx.x >> 6, lane = threadIdx.x & 63;
    int row = blockIdx.x * 4 + wave;
    if (row >= NUM_WORDS) return;
    float acc = 0.f;
    for (int h = lane; h < HIDDEN; h += 64) acc += doc[row * HIDDEN + h] * hw[h];
    for (int off = 32; off > 0; off >>= 1) acc += __shfl_down(acc, off);
    if (lane == 0) out[row] = acc + hb[0];
}

// ---------------- width prior ffnn: [30,20] -> [30] ----------------
__global__ void width_kernel(const float* __restrict__ x, const float* __restrict__ w1,
                             const float* __restrict__ b1, const float* __restrict__ w2,
                             const float* __restrict__ b2, const float* __restrict__ w3,
                             const float* __restrict__ b3, float* __restrict__ out) {
    __shared__ float xs[FEAT];
    __shared__ float h1s[FFNN_DIM];
    __shared__ float red[256];
    int r = blockIdx.x, t = threadIdx.x;
    if (t < FEAT) xs[t] = x[r * FEAT + t];
    __syncthreads();
    for (int j = t; j < FFNN_DIM; j += 256) {
        float acc = b1[j];
        for (int k = 0; k < FEAT; ++k) acc += xs[k] * w1[k * FFNN_DIM + j];
        h1s[j] = fmaxf(acc, 0.f);
    }
    __syncthreads();
    float partial = 0.f;
    for (int j = t; j < FFNN_DIM; j += 256) {
        float acc = b2[j];
        for (int k = 0; k < FFNN_DIM; ++k) acc += h1s[k] * w2[k * FFNN_DIM + j];
        partial += fmaxf(acc, 0.f) * w3[j];
    }
    red[t] = partial;
    __syncthreads();
    for (int s = 128; s > 0; s >>= 1) { if (t < s) red[t] += red[t + s]; __syncthreads(); }
    if (t == 0) out[r] = red[0] + b3[0];
}

// ---------------- attention weights per span: attn_g [8192][32] ----------------
__global__ void attn_kernel(const float* __restrict__ head_s, const int* __restrict__ starts,
                            const int* __restrict__ ends, float* __restrict__ attn_g) {
    int wave = threadIdx.x >> 6, w = threadIdx.x & 63;
    int c = blockIdx.x * 4 + wave;
    if (c >= NUM_CAND) return;
    int s = starts[c], e = ends[c];
    int wid = e - s;
    float hsv = -INFINITY;
    if (w < MSW && w <= wid) hsv = head_s[s + w];
    float m = hsv;
    for (int off = 32; off > 0; off >>= 1) m = fmaxf(m, __shfl_down(m, off));
    m = __shfl(m, 0);
    float ex = (w < MSW && w <= wid) ? expf(hsv - m) : 0.f;
    float ssum = ex;
    for (int off = 32; off > 0; off >>= 1) ssum += __shfl_down(ssum, off);
    ssum = __shfl(ssum, 0);
    if (w < 32) attn_g[c * 32 + w] = (w < MSW) ? (ex / ssum) : 0.f;
}

// ---------------- doc fp32 -> 3-split bf16 [2048*768] ----------------
__global__ void doc_convert(const float* __restrict__ doc, unsigned short* __restrict__ d0,
                            unsigned short* __restrict__ d1, unsigned short* __restrict__ d2) {
    int i = blockIdx.x * 256 + threadIdx.x;
    if (i < NUM_WORDS * HIDDEN) store_split3(d0, d1, d2, i, doc[i]);
}

// ---------------- weight convert+transpose: w[K][N] -> 3-split [gridDim.y][Kp] ------------
__global__ void convert_wt(const float* __restrict__ w, int K, int N, int Kp,
                           unsigned short* __restrict__ q0, unsigned short* __restrict__ q1,
                           unsigned short* __restrict__ q2) {
    int n = blockIdx.y;
    int k = blockIdx.x * blockDim.x + threadIdx.x;
    if (k >= Kp) return;
    float v = (k < K && n < N) ? w[(size_t)k * N + n] : 0.f;
    store_split3(q0, q1, q2, (size_t)n * Kp + k, v);
}

// ---------------- T_w[wid][1024] = span_width_emb[wid] @ m_w1[1536:1556] ----------------
__global__ void tw_kernel(const float* __restrict__ swe, const float* __restrict__ w1,
                          float* __restrict__ tw) {
    int wid = blockIdx.x, t = threadIdx.x;
    for (int n = t; n < NP; n += 256) {
        float acc = 0.f;
        if (n < FFNN_DIM) {
            for (int f = 0; f < FEAT; ++f)
                acc += swe[wid * FEAT + f] * w1[(size_t)(1536 + f) * FFNN_DIM + n];
        }
        tw[wid * NP + n] = acc;
    }
}

// Stage one 128x32-bf16 tile (8KB) async into LDS with XOR swizzle.
__device__ __forceinline__ void stage_tile(const unsigned short* __restrict__ src,
                                           unsigned short* lds, int base_row, int Kp, int k0,
                                           int t) {
#pragma unroll
    for (int qi = 0; qi < 2; ++qi) {
        int u = qi * 256 + t;
        int l = u & 63;
        int row = ((u >> 6) << 4) + (l >> 2);
        int cblk = (l & 3) ^ (row & 3);
        const unsigned short* g = src + (size_t)(base_row + row) * Kp + k0 + cblk * 8;
        gl_lds16(g, lds + u * 8);
    }
}

// ---------------- 3-split 6-product MFMA GEMM, fp32 out: P = doc @ [W_s|W_e|W_a] ---------
__global__ __launch_bounds__(256, 2) void gemm6p(
    const unsigned short* __restrict__ A0, const unsigned short* __restrict__ A1,
    const unsigned short* __restrict__ A2,
    const unsigned short* __restrict__ B0, const unsigned short* __restrict__ B1,
    const unsigned short* __restrict__ B2,
    float* __restrict__ C) {
    __shared__ unsigned short As0[128 * 32], As1[128 * 32], As2[128 * 32];
    __shared__ unsigned short Bs0[128 * 32], Bs1[128 * 32], Bs2[128 * 32];
    int t = threadIdx.x;
    int bid = blockIdx.x;
    int bm = (bid & 15) << 7;
    int bn = (bid >> 4) << 7;
    int lane = t & 63, wv = t >> 6;
    int wm = (wv >> 1) * 64, wn = (wv & 1) * 64;
    int lr = lane & 15, qq = lane >> 4;
    int sw = (qq ^ (lr & 3)) * 8;

    f32x4 acc[4][4] = {};

    for (int k0 = 0; k0 < HIDDEN; k0 += 32) {
        stage_tile(A0, As0, bm, HIDDEN, k0, t);
        stage_tile(A1, As1, bm, HIDDEN, k0, t);
        stage_tile(A2, As2, bm, HIDDEN, k0, t);
        stage_tile(B0, Bs0, bn, HIDDEN, k0, t);
        stage_tile(B1, Bs1, bn, HIDDEN, k0, t);
        stage_tile(B2, Bs2, bn, HIDDEN, k0, t);
        __syncthreads();
        short8 a0[4], a1[4], a2[4];
#pragma unroll
        for (int i = 0; i < 4; ++i) {
            int ra = (wm + i * 16 + lr) * 32 + sw;
            a0[i] = *(const short8*)&As0[ra];
            a1[i] = *(const short8*)&As1[ra];
            a2[i] = *(const short8*)&As2[ra];
        }
#pragma unroll
        for (int j = 0; j < 4; ++j) {
            int rb = (wn + j * 16 + lr) * 32 + sw;
            short8 b0 = *(const short8*)&Bs0[rb];
            short8 b1 = *(const short8*)&Bs1[rb];
            short8 b2 = *(const short8*)&Bs2[rb];
#pragma unroll
            for (int i = 0; i < 4; ++i) {
                acc[i][j] = __builtin_amdgcn_mfma_f32_16x16x32_bf16(a2[i], b0, acc[i][j], 0, 0, 0);
                acc[i][j] = __builtin_amdgcn_mfma_f32_16x16x32_bf16(a0[i], b2, acc[i][j], 0, 0, 0);
                acc[i][j] = __builtin_amdgcn_mfma_f32_16x16x32_bf16(a1[i], b1, acc[i][j], 0, 0, 0);
                acc[i][j] = __builtin_amdgcn_mfma_f32_16x16x32_bf16(a1[i], b0, acc[i][j], 0, 0, 0);
                acc[i][j] = __builtin_amdgcn_mfma_f32_16x16x32_bf16(a0[i], b1, acc[i][j], 0, 0, 0);
                acc[i][j] = __builtin_amdgcn_mfma_f32_16x16x32_bf16(a0[i], b0, acc[i][j], 0, 0, 0);
            }
        }
        __syncthreads();
    }
#pragma unroll
    for (int i = 0; i < 4; ++i)
#pragma unroll
        for (int j = 0; j < 4; ++j)
#pragma unroll
            for (int r = 0; r < 4; ++r) {
                int m = bm + wm + i * 16 + qq * 4 + r;
                int n = bn + wn + j * 16 + lr;
                C[(size_t)m * PNP + n] = acc[i][j][r];
            }
}

// ---------------- combine: h1[c] = relu(P_s[s] + P_e[e] + sum attn*P_a[s+w] + Tw + b1) ----
__global__ void combine_kernel(const float* __restrict__ P, const float* __restrict__ tw,
                               const float* __restrict__ attn_g, const float* __restrict__ b1,
                               const int* __restrict__ starts, const int* __restrict__ ends,
                               unsigned short* __restrict__ h0, unsigned short* __restrict__ h1,
                               unsigned short* __restrict__ h2) {
    int c = blockIdx.x, t = threadIdx.x;
    int s = starts[c], e = ends[c];
    int wid = e - s;
    __shared__ float at[MSW];
    if (t < MSW) at[t] = attn_g[c * 32 + t];
    __syncthreads();
    const float* Ps = P + (size_t)s * PNP;
    const float* Pe = P + (size_t)e * PNP + 1024;
    const float* Pa = P + (size_t)s * PNP + 2048;
    const float* Tw = tw + (size_t)wid * NP;
    for (int n = t; n < NP; n += 256) {
        if (n < FFNN_DIM) {
            float acc = Ps[n] + Pe[n] + Tw[n] + b1[n];
            for (int w = 0; w <= wid; ++w) acc += at[w] * Pa[(size_t)w * PNP + n];
            store_split3(h0, h1, h2, (size_t)c * NP + n, fmaxf(acc, 0.f));
        } else {
            h0[(size_t)c * NP + n] = 0;
            h1[(size_t)c * NP + n] = 0;
            h2[(size_t)c * NP + n] = 0;
        }
    }
}

// ---------------- 3-split 6-product MFMA GEMM (score fusion) ------------
__global__ __launch_bounds__(256, 2) void gemm6(
    const unsigned short* __restrict__ A0, const unsigned short* __restrict__ A1,
    const unsigned short* __restrict__ A2,
    const unsigned short* __restrict__ B0, const unsigned short* __restrict__ B1,
    const unsigned short* __restrict__ B2,
    const float* __restrict__ bias, int nreal, int Kp,
    const float* __restrict__ w3, float* __restrict__ partials) {
    __shared__ unsigned short As0[128 * 32], As1[128 * 32], As2[128 * 32];
    __shared__ unsigned short Bs0[128 * 32], Bs1[128 * 32], Bs2[128 * 32];
    int t = threadIdx.x;
    int bid = blockIdx.x;
    int sm = bid >> 6, idx = bid & 63;
    int bm = ((sm << 3) + (idx & 7)) << 7;
    int bn = (idx >> 3) << 7;
    int lane = t & 63, wv = t >> 6;
    int wm = (wv >> 1) * 64, wn = (wv & 1) * 64;
    int lr = lane & 15, qq = lane >> 4;
    int sw = (qq ^ (lr & 3)) * 8;

    f32x4 acc[4][4] = {};

    for (int k0 = 0; k0 < Kp; k0 += 32) {
        stage_tile(A0, As0, bm, Kp, k0, t);
        stage_tile(A1, As1, bm, Kp, k0, t);
        stage_tile(A2, As2, bm, Kp, k0, t);
        stage_tile(B0, Bs0, bn, Kp, k0, t);
        stage_tile(B1, Bs1, bn, Kp, k0, t);
        stage_tile(B2, Bs2, bn, Kp, k0, t);
        __syncthreads();
        short8 a0[4], a1[4], a2[4];
#pragma unroll
        for (int i = 0; i < 4; ++i) {
            int ra = (wm + i * 16 + lr) * 32 + sw;
            a0[i] = *(const short8*)&As0[ra];
            a1[i] = *(const short8*)&As1[ra];
            a2[i] = *(const short8*)&As2[ra];
        }
#pragma unroll
        for (int j = 0; j < 4; ++j) {
            int rb = (wn + j * 16 + lr) * 32 + sw;
            short8 b0 = *(const short8*)&Bs0[rb];
            short8 b1 = *(const short8*)&Bs1[rb];
            short8 b2 = *(const short8*)&Bs2[rb];
#pragma unroll
            for (int i = 0; i < 4; ++i) {
                acc[i][j] = __builtin_amdgcn_mfma_f32_16x16x32_bf16(a2[i], b0, acc[i][j], 0, 0, 0);
                acc[i][j] = __builtin_amdgcn_mfma_f32_16x16x32_bf16(a0[i], b2, acc[i][j], 0, 0, 0);
                acc[i][j] = __builtin_amdgcn_mfma_f32_16x16x32_bf16(a1[i], b1, acc[i][j], 0, 0, 0);
                acc[i][j] = __builtin_amdgcn_mfma_f32_16x16x32_bf16(a1[i], b0, acc[i][j], 0, 0, 0);
                acc[i][j] = __builtin_amdgcn_mfma_f32_16x16x32_bf16(a0[i], b1, acc[i][j], 0, 0, 0);
                acc[i][j] = __builtin_amdgcn_mfma_f32_16x16x32_bf16(a0[i], b0, acc[i][j], 0, 0, 0);
            }
        }
        __syncthreads();
    }

    int pid = ((bn >> 7) << 1) | (wn >> 6);  // 0..15
#pragma unroll
    for (int i = 0; i < 4; ++i)
#pragma unroll
        for (int r = 0; r < 4; ++r) {
            float p = 0.f;
#pragma unroll
            for (int j = 0; j < 4; ++j) {
                int n = bn + wn + j * 16 + lr;
                float v = acc[i][j][r] + (n < nreal ? bias[n] : 0.f);
                v = fmaxf(v, 0.f);
                p += v * (n < nreal ? w3[n] : 0.f);
            }
            p += __shfl_xor(p, 1);
            p += __shfl_xor(p, 2);
            p += __shfl_xor(p, 4);
            p += __shfl_xor(p, 8);
            if (lr == 0) {
                int m = bm + wm + i * 16 + qq * 4 + r;
                partials[(size_t)m * 16 + pid] = p;
            }
        }
}

// ---------------- deterministic score finalize ----------------
__global__ void score_final(const float* __restrict__ partials, const float* __restrict__ b3,
                            const float* __restrict__ width_s, const int* __restrict__ starts,
                            const int* __restrict__ ends, float* __restrict__ out) {
    int c = blockIdx.x * 256 + threadIdx.x;
    if (c >= NUM_CAND) return;
    float s = b3[0] + width_s[ends[c] - starts[c]];
#pragma unroll
    for (int p = 0; p < 16; ++p) s += partials[(size_t)c * 16 + p];
    out[c] = s;
}

// ---------------- exact counting rank-sort: 256 blocks ----------------
__global__ __launch_bounds__(256) void rank_kernel(const float* __restrict__ scores,
                                                   const int* __restrict__ starts,
                                                   const int* __restrict__ ends,
                                                   unsigned short* __restrict__ ord_g,
                                                   unsigned int* __restrict__ se_g) {
    __shared__ unsigned long long kk[NUM_CAND];  // 64 KB
    int t = threadIdx.x;
    for (int i = t; i < NUM_CAND; i += 256) {
        unsigned int b = __float_as_uint(scores[i]);
        unsigned int u = b ^ ((b & 0x80000000u) ? 0xFFFFFFFFu : 0x80000000u);
        unsigned int hi = ~u;
        kk[i] = ((unsigned long long)hi << 32) | (unsigned int)i;
    }
    __syncthreads();
    int c = blockIdx.x * 32 + (t >> 3);
    int seg = (t & 7) * 1024;
    unsigned long long mykey = kk[c];
    int cnt = 0;
    for (int i = seg; i < seg + 1024; ++i) cnt += (kk[i] < mykey) ? 1 : 0;
    cnt += __shfl_xor(cnt, 1);
    cnt += __shfl_xor(cnt, 2);
    cnt += __shfl_xor(cnt, 4);
    if ((t & 7) == 0) {
        int idx = (int)(mykey & 0xFFFFFFFFull);
        int rank = cnt;
        ord_g[rank] = (unsigned short)idx;
        se_g[rank] = ((unsigned int)starts[idx] << 16) | (unsigned int)ends[idx];
    }
}

// ---------------- multi-wave pipelined greedy crossing-NMS ----------------
// 8 waves. Round r: wave w evaluates chunk 8r+w (64 candidates) against round-start state
// in parallel. Commits serialize in 8 barrier phases; in phase p, wave p first applies the
// closed-form fix-up for chunk p-1's accepts (published in lst[]), then runs the verified
// ballot-accept loop; waves >p apply the same fix-ups concurrently. st flushes are
// fire-and-forget (re-read only at next round's eval, after barriers). Decision logic is
// byte-identical to the r2..r12-verified form; cross-chunk patching = r11's verified
// "lo patches hi" algebra, generalized across waves.
__global__ __launch_bounds__(512) void select_nms(const unsigned int* __restrict__ se_g,
                                                  unsigned short* __restrict__ sel_g,
                                                  int* __restrict__ count_g) {
    __shared__ unsigned int se_arr[NUM_CAND];   // 32 KB
    __shared__ unsigned int st[2 * NUM_WORDS];  // 16 KB
    __shared__ unsigned int lst[512];           //  2 KB accepts this round
    __shared__ int pos[9];                      // per-chunk accept-list offsets
    __shared__ int count_sh;
    int t = threadIdx.x;
    int wv = t >> 6, lane = t & 63;

    for (int i = t; i < NUM_CAND; i += 512) se_arr[i] = se_g[i];
    for (int i = t; i < 2 * NUM_WORDS; i += 512)
        st[i] = (i & 1) ? (unsigned int)NUM_WORDS : 0u;  // max_end+1=0, min_start=2048
    if (t == 0) count_sh = 0;
    __syncthreads();

    const unsigned long long* stp = (const unsigned long long*)st;
    for (int r = 0; r < NUM_CAND / 512; ++r) {
        int ib = r * 512 + wv * 64;  // this wave's chunk base rank
        unsigned int sev = se_arr[ib + lane];
        int s = (int)(sev >> 16), e = (int)(sev & 0xFFFFu);
        const unsigned long long* bp = stp + s;
        unsigned long long v[MSW];
#pragma unroll
        for (int w = 0; w < MSW; ++w) v[w] = bp[w];
        int me = (int)(unsigned int)v[0] - 1;
        bool crossed = (s < e) && ((int)(unsigned int)(v[0] >> 32) < s);
#pragma unroll
        for (int w = 1; w < MSW; ++w) {
            int j = s + w;
            bool in = (j <= e);
            int mej = (int)(unsigned int)v[w] - 1;
            int msj = (int)(unsigned int)(v[w] >> 32);
            crossed = crossed || (in && ((mej > e) || ((j < e) && (msj < s))));
        }
        bool spec = !crossed && (me != e);
        if (t == 0) pos[0] = 0;
        __syncthreads();

        for (int p = 0; p < 8; ++p) {
            if (p > 0 && wv >= p) {
                // apply fix-ups for chunk p-1's accepts (ranks strictly earlier than ours)
                int lo = pos[p - 1], hi = pos[p];
                for (int k = lo; k < hi; ++k) {
                    unsigned int sef = lst[k];
                    int sf = (int)(sef >> 16), ef = (int)(sef & 0xFFFFu);
                    if (s == sf) me = max(me, ef);
                    crossed = crossed || ((s < sf) && (sf <= e) && (ef > e))
                                      || ((sf < s) && (s <= ef) && (ef < e));
                }
                spec = !crossed && (me != e);
            }
            if (wv == p) {
                int cbefore = count_sh;
                int lbase = pos[p];
                if (cbefore < TOP_NUM) {
                    int count = cbefore;
                    unsigned long long window = ~0ull;
                    unsigned int pend = 0u;
                    int rk = 0, lcnt = 0;
                    while (true) {
                        unsigned long long b = __ballot(spec) & window;
                        if (b == 0ull) break;
                        int f = __ffsll((unsigned long long)b) - 1;
                        unsigned int sef = __builtin_amdgcn_readlane(sev, (unsigned int)f);
                        int sf = (int)(sef >> 16), ef = (int)(sef & 0xFFFFu);
                        bool mine = (lane == lcnt);
                        pend = mine ? sef : pend;
                        rk = mine ? (ib + f) : rk;
                        lcnt++;
                        count++;
                        if (count >= TOP_NUM) break;
                        window &= (f >= 63) ? 0ull : (~0ull << (f + 1));
                        if (lane > f) {
                            if (s == sf) me = max(me, ef);
                            crossed = crossed || ((s < sf) && (sf <= e) && (ef > e))
                                              || ((sf < s) && (s <= ef) && (ef < e));
                            spec = !crossed && (me != e);
                        }
                    }
                    if (lane < lcnt) {
                        int sf = (int)(pend >> 16), ef = (int)(pend & 0xFFFFu);
                        sel_g[cbefore + lane] = (unsigned short)rk;
                        lst[lbase + lane] = pend;
                        atomicMax(&st[2 * sf], (unsigned int)(ef + 1));
                        atomicMin(&st[2 * ef + 1], (unsigned int)sf);
                    }
                    if (lane == 0) {
                        count_sh = count;
                        pos[p + 1] = lbase + lcnt;
                    }
                } else {
                    if (lane == 0) pos[p + 1] = lbase;
                }
            }
            __syncthreads();
        }
        if (count_sh >= TOP_NUM) break;
    }
    if (t == 0) *count_g = count_sh;
}

// ---------------- post: final span-order sort + emit ----------------
__global__ __launch_bounds__(256) void select_post(const float* __restrict__ scores,
                                                   const int* __restrict__ starts,
                                                   const int* __restrict__ ends,
                                                   const unsigned short* __restrict__ ord_g,
                                                   const unsigned short* __restrict__ sel_g,
                                                   const int* __restrict__ count_g,
                                                   float* out, int* top_idx_ws) {
    __shared__ unsigned long long fkeys[1024];
    int t = threadIdx.x;
    int count = *count_g;
    for (int i = t; i < 1024; i += 256) {
        unsigned long long k = 0xFFFFFFFFFFFFFFFFull;
        if (i < count) {
            int idx = (int)ord_g[sel_g[i]];
            unsigned int key32 = (unsigned int)(starts[idx] * NUM_WORDS + ends[idx]);
            k = ((unsigned long long)key32 << 32) | (unsigned int)idx;
        }
        fkeys[i] = k;
    }
    __syncthreads();
    for (int size = 2; size <= 1024; size <<= 1) {
        for (int stride = size >> 1; stride > 0; stride >>= 1) {
            for (int i = t; i < 1024; i += 256) {
                int ixj = i ^ stride;
                if (ixj > i) {
                    bool up = ((i & size) == 0);
                    unsigned long long a = fkeys[i], b = fkeys[ixj];
                    if ((a > b) == up) { fkeys[i] = b; fkeys[ixj] = a; }
                }
            }
            __syncthreads();
        }
    }
    for (int i = t; i < TOP_NUM; i += 256) {
        int fi = (i < count) ? (int)(fkeys[i] & 0xFFFFFFFFull)
                             : (int)(fkeys[0] & 0xFFFFFFFFull);
        out[OUT_TOPIDX + i] = (float)fi;
        out[OUT_TSTART + i] = (float)starts[fi];
        out[OUT_TEND + i] = (float)ends[fi];
        out[OUT_TSCORE + i] = scores[fi];
        top_idx_ws[i] = fi;
    }
}

// ---------------- gather top_span_emb rows directly from doc (exact fp32) ----------------
__global__ void gather_emb(const float* __restrict__ doc, const float* __restrict__ swe,
                           const float* __restrict__ attn_g, const int* __restrict__ starts,
                           const int* __restrict__ ends, const int* __restrict__ top_idx_ws,
                           float* __restrict__ out) {
    int r = blockIdx.x, t = threadIdx.x;
    int idx = top_idx_ws[r];
    int s = starts[idx], e = ends[idx];
    int wid = e - s;
    __shared__ float at[MSW];
    if (t < MSW) at[t] = attn_g[(size_t)idx * 32 + t];
    __syncthreads();
    float* dst = out + OUT_TEMB + (size_t)r * SPAN_DIM;
    for (int h = t; h < HIDDEN; h += 256) {
        dst[h] = doc[(size_t)s * HIDDEN + h];
        dst[HIDDEN + h] = doc[(size_t)e * HIDDEN + h];
        float acc = 0.f;
        for (int w = 0; w <= wid; ++w) acc += at[w] * doc[(size_t)(s + w) * HIDDEN + h];
        dst[2 * HIDDEN + FEAT + h] = acc;
    }
    if (t < FEAT) dst[2 * HIDDEN + t] = swe[wid * FEAT + t];
}

extern "C" void kernel_launch(void* const* d_in, const int* in_sizes, int n_in,
                              void* d_out, int out_size, void* d_ws, size_t ws_size,
                              hipStream_t stream) {
    const float* mention_doc = (const float*)d_in[0];
    const float* span_width_emb = (const float*)d_in[1];
    const float* head_w = (const float*)d_in[2];
    const float* head_b = (const float*)d_in[3];
    const float* m_w1 = (const float*)d_in[4];
    const float* m_b1 = (const float*)d_in[5];
    const float* m_w2 = (const float*)d_in[6];
    const float* m_b2 = (const float*)d_in[7];
    const float* m_w3 = (const float*)d_in[8];
    const float* m_b3 = (const float*)d_in[9];
    const float* width_prior_emb = (const float*)d_in[10];
    const float* w_w1 = (const float*)d_in[11];
    const float* w_b1 = (const float*)d_in[12];
    const float* w_w2 = (const float*)d_in[13];
    const float* w_b2 = (const float*)d_in[14];
    const float* w_w3 = (const float*)d_in[15];
    const float* w_b3 = (const float*)d_in[16];
    const int* cand_starts = (const int*)d_in[17];
    const int* cand_ends = (const int*)d_in[18];

    char* w = (char*)d_ws;
    const size_t szH = (size_t)NUM_CAND * NP * 2;
    const size_t szW2 = (size_t)NP * KP2 * 2;
    const size_t szWc = (size_t)PNP * HIDDEN * 2;
    const size_t szD = (size_t)NUM_WORDS * HIDDEN * 2;
    char* p = w;
    unsigned short* h0 = (unsigned short*)p; p += szH;
    unsigned short* h1 = (unsigned short*)p; p += szH;
    unsigned short* h2 = (unsigned short*)p; p += szH;
    unsigned short* w2t0 = (unsigned short*)p; p += szW2;
    unsigned short* w2t1 = (unsigned short*)p; p += szW2;
    unsigned short* w2t2 = (unsigned short*)p; p += szW2;
    unsigned short* Wc0 = (unsigned short*)p; p += szWc;
    unsigned short* Wc1 = (unsigned short*)p; p += szWc;
    unsigned short* Wc2 = (unsigned short*)p; p += szWc;
    unsigned short* d0 = (unsigned short*)p; p += szD;
    unsigned short* d1 = (unsigned short*)p; p += szD;
    unsigned short* d2 = (unsigned short*)p; p += szD;
    float* P = (float*)p; p += (size_t)NUM_WORDS * PNP * 4;
    float* tw = (float*)p; p += (size_t)MSW * NP * 4;
    float* attn_g = (float*)p; p += (size_t)NUM_CAND * 32 * 4;
    float* partials = (float*)p; p += (size_t)NUM_CAND * 16 * 4;
    unsigned short* ord_g = (unsigned short*)p; p += (size_t)NUM_CAND * 2;
    unsigned int* se_g = (unsigned int*)p; p += (size_t)NUM_CAND * 4;
    unsigned short* sel_g = (unsigned short*)p; p += 2048;
    int* count_g = (int*)p; p += 128;
    float* head_s = (float*)p; p += NUM_WORDS * 4;
    float* width_s = (float*)p; p += 128;
    int* top_idx_ws = (int*)p; p += 4096;

    size_t need = (size_t)(p - w);
    if (ws_size < need) {
        fprintf(stderr, "kernel_launch: ws too small (%zu < %zu)\n", ws_size, need);
    }

    float* out = (float*)d_out;

    head_kernel<<<NUM_WORDS / 4, 256, 0, stream>>>(mention_doc, head_w, head_b, head_s);
    width_kernel<<<MSW, 256, 0, stream>>>(width_prior_emb, w_w1, w_b1, w_w2, w_b2, w_w3, w_b3,
                                          width_s);
    attn_kernel<<<NUM_CAND / 4, 256, 0, stream>>>(head_s, cand_starts, cand_ends, attn_g);
    doc_convert<<<(NUM_WORDS * HIDDEN + 255) / 256, 256, 0, stream>>>(mention_doc, d0, d1, d2);
    convert_wt<<<dim3(3, 1024), 256, 0, stream>>>(m_w1, HIDDEN, FFNN_DIM, HIDDEN,
                                                  Wc0, Wc1, Wc2);
    convert_wt<<<dim3(3, 1024), 256, 0, stream>>>(m_w1 + (size_t)HIDDEN * FFNN_DIM, HIDDEN,
                                                  FFNN_DIM, HIDDEN,
                                                  Wc0 + (size_t)1024 * HIDDEN,
                                                  Wc1 + (size_t)1024 * HIDDEN,
                                                  Wc2 + (size_t)1024 * HIDDEN);
    convert_wt<<<dim3(3, 1024), 256, 0, stream>>>(m_w1 + (size_t)1556 * FFNN_DIM, HIDDEN,
                                                  FFNN_DIM, HIDDEN,
                                                  Wc0 + (size_t)2048 * HIDDEN,
                                                  Wc1 + (size_t)2048 * HIDDEN,
                                                  Wc2 + (size_t)2048 * HIDDEN);
    convert_wt<<<dim3(4, 1024), 256, 0, stream>>>(m_w2, FFNN_DIM, FFNN_DIM, KP2,
                                                  w2t0, w2t1, w2t2);
    tw_kernel<<<MSW, 256, 0, stream>>>(span_width_emb, m_w1, tw);
    gemm6p<<<16 * 24, 256, 0, stream>>>(d0, d1, d2, Wc0, Wc1, Wc2, P);
    combine_kernel<<<NUM_CAND, 256, 0, stream>>>(P, tw, attn_g, m_b1, cand_starts, cand_ends,
                                                 h0, h1, h2);
    gemm6<<<512, 256, 0, stream>>>(h0, h1, h2, w2t0, w2t1, w2t2, m_b2, FFNN_DIM, KP2,
                                   m_w3, partials);
    score_final<<<NUM_CAND / 256, 256, 0, stream>>>(partials, m_b3, width_s, cand_starts,
                                                    cand_ends, out);
    rank_kernel<<<NUM_CAND / 32, 256, 0, stream>>>(out, cand_starts, cand_ends, ord_g, se_g);
    select_nms<<<1, 512, 0, stream>>>(se_g, sel_g, count_g);
    select_post<<<1, 256, 0, stream>>>(out, cand_starts, cand_ends, ord_g, sel_g, count_g,
                                       out, top_idx_ws);
    gather_emb<<<TOP_NUM, 256, 0, stream>>>(mention_doc, span_width_emb, attn_g, cand_starts,
                                            cand_ends, top_idx_ws, out);
}

// Round 14
// 894.294 us; speedup vs baseline: 1.0809x; 1.0086x over previous
//
#include <hip/hip_runtime.h>
#include <cstdio>
#include <cmath>

#define NUM_WORDS 2048
#define NUM_CAND 8192
#define HIDDEN 768
#define FEAT 20
#define FFNN_DIM 1000
#define SPAN_DIM 2324
#define TOP_NUM 819
#define MSW 30
#define KP2 1024   // FFNN padded to x32
#define NP 1024    // padded N
#define PNP 3072   // P matrix padded N (3 segments of 1024)

// d_out layout (floats): [scores 8192][top_idx 819][top_starts 819][top_ends 819]
//                        [top_span_emb 819*2324][top_scores 819]
#define OUT_TOPIDX   (NUM_CAND)
#define OUT_TSTART   (NUM_CAND + TOP_NUM)
#define OUT_TEND     (NUM_CAND + 2*TOP_NUM)
#define OUT_TEMB     (NUM_CAND + 3*TOP_NUM)
#define OUT_TSCORE   (NUM_CAND + 3*TOP_NUM + TOP_NUM*SPAN_DIM)

typedef short short8 __attribute__((ext_vector_type(8)));
typedef float f32x4 __attribute__((ext_vector_type(4)));

__device__ __forceinline__ unsigned short bf16_rne(float x) {
    unsigned int u = __float_as_uint(x);
    unsigned int r = u + 0x7FFFu + ((u >> 16) & 1u);
    return (unsigned short)(r >> 16);
}
__device__ __forceinline__ float bf16_to_f(unsigned short h) {
    return __uint_as_float(((unsigned int)h) << 16);
}
// 3-way split: v = s0 + s1 + s2 + r, |r| <= 2^-27 |v|
__device__ __forceinline__ void store_split3(unsigned short* p0, unsigned short* p1,
                                             unsigned short* p2, size_t off, float v) {
    unsigned short h0 = bf16_rne(v);
    float r1 = v - bf16_to_f(h0);
    unsigned short h1 = bf16_rne(r1);
    float r2 = r1 - bf16_to_f(h1);
    p0[off] = h0;
    p1[off] = h1;
    p2[off] = bf16_rne(r2);
}

// async 16B global->LDS (gfx950 global_load_lds_dwordx4). LDS dest must be
// wave-uniform base + lane*16 -> staging tiles are UNPADDED (128x32 bf16, 64B rows),
// bank conflicts handled by XOR swizzle: kblk stored at kblk^(row&3).
__device__ __forceinline__ void gl_lds16(const unsigned short* g, unsigned short* l) {
    __builtin_amdgcn_global_load_lds(
        (const __attribute__((address_space(1))) unsigned short*)g,
        (__attribute__((address_space(3))) unsigned short*)l, 16, 0, 0);
}

// ---------------- head scores: doc @ head_w + head_b  -> [2048] ----------------
__global__ void head_kernel(const float* __restrict__ doc, const float* __restrict__ hw,
                            const float* __restrict__ hb, float* __restrict__ out) {
    int wave = threadIdx.x >> 6, lane = threadIdx.x & 63;
    int row = blockIdx.x * 4 + wave;
    if (row >= NUM_WORDS) return;
    float acc = 0.f;
    for (int h = lane; h < HIDDEN; h += 64) acc += doc[row * HIDDEN + h] * hw[h];
    for (int off = 32; off > 0; off >>= 1) acc += __shfl_down(acc, off);
    if (lane == 0) out[row] = acc + hb[0];
}

// ---------------- width prior ffnn: [30,20] -> [30] ----------------
__global__ void width_kernel(const float* __restrict__ x, const float* __restrict__ w1,
                             const float* __restrict__ b1, const float* __restrict__ w2,
                             const float* __restrict__ b2, const float* __restrict__ w3,
                             const float* __restrict__ b3, float* __restrict__ out) {
    __shared__ float xs[FEAT];
    __shared__ float h1s[FFNN_DIM];
    __shared__ float red[256];
    int r = blockIdx.x, t = threadIdx.x;
    if (t < FEAT) xs[t] = x[r * FEAT + t];
    __syncthreads();
    for (int j = t; j < FFNN_DIM; j += 256) {
        float acc = b1[j];
        for (int k = 0; k < FEAT; ++k) acc += xs[k] * w1[k * FFNN_DIM + j];
        h1s[j] = fmaxf(acc, 0.f);
    }
    __syncthreads();
    float partial = 0.f;
    for (int j = t; j < FFNN_DIM; j += 256) {
        float acc = b2[j];
        for (int k = 0; k < FFNN_DIM; ++k) acc += h1s[k] * w2[k * FFNN_DIM + j];
        partial += fmaxf(acc, 0.f) * w3[j];
    }
    red[t] = partial;
    __syncthreads();
    for (int s = 128; s > 0; s >>= 1) { if (t < s) red[t] += red[t + s]; __syncthreads(); }
    if (t == 0) out[r] = red[0] + b3[0];
}

// ---------------- attention weights per span: attn_g [8192][32] ----------------
__global__ void attn_kernel(const float* __restrict__ head_s, const int* __restrict__ starts,
                            const int* __restrict__ ends, float* __restrict__ attn_g) {
    int wave = threadIdx.x >> 6, w = threadIdx.x & 63;
    int c = blockIdx.x * 4 + wave;
    if (c >= NUM_CAND) return;
    int s = starts[c], e = ends[c];
    int wid = e - s;
    float hsv = -INFINITY;
    if (w < MSW && w <= wid) hsv = head_s[s + w];
    float m = hsv;
    for (int off = 32; off > 0; off >>= 1) m = fmaxf(m, __shfl_down(m, off));
    m = __shfl(m, 0);
    float ex = (w < MSW && w <= wid) ? expf(hsv - m) : 0.f;
    float ssum = ex;
    for (int off = 32; off > 0; off >>= 1) ssum += __shfl_down(ssum, off);
    ssum = __shfl(ssum, 0);
    if (w < 32) attn_g[c * 32 + w] = (w < MSW) ? (ex / ssum) : 0.f;
}

// ---------------- doc fp32 -> 3-split bf16 [2048*768] ----------------
__global__ void doc_convert(const float* __restrict__ doc, unsigned short* __restrict__ d0,
                            unsigned short* __restrict__ d1, unsigned short* __restrict__ d2) {
    int i = blockIdx.x * 256 + threadIdx.x;
    if (i < NUM_WORDS * HIDDEN) store_split3(d0, d1, d2, i, doc[i]);
}

// ---------------- weight convert+transpose: w[K][N] -> 3-split [gridDim.y][Kp] ------------
__global__ void convert_wt(const float* __restrict__ w, int K, int N, int Kp,
                           unsigned short* __restrict__ q0, unsigned short* __restrict__ q1,
                           unsigned short* __restrict__ q2) {
    int n = blockIdx.y;
    int k = blockIdx.x * blockDim.x + threadIdx.x;
    if (k >= Kp) return;
    float v = (k < K && n < N) ? w[(size_t)k * N + n] : 0.f;
    store_split3(q0, q1, q2, (size_t)n * Kp + k, v);
}

// ---------------- T_w[wid][1024] = span_width_emb[wid] @ m_w1[1536:1556] ----------------
__global__ void tw_kernel(const float* __restrict__ swe, const float* __restrict__ w1,
                          float* __restrict__ tw) {
    int wid = blockIdx.x, t = threadIdx.x;
    for (int n = t; n < NP; n += 256) {
        float acc = 0.f;
        if (n < FFNN_DIM) {
            for (int f = 0; f < FEAT; ++f)
                acc += swe[wid * FEAT + f] * w1[(size_t)(1536 + f) * FFNN_DIM + n];
        }
        tw[wid * NP + n] = acc;
    }
}

// Stage one 128x32-bf16 tile (8KB) async into LDS with XOR swizzle.
__device__ __forceinline__ void stage_tile(const unsigned short* __restrict__ src,
                                           unsigned short* lds, int base_row, int Kp, int k0,
                                           int t) {
#pragma unroll
    for (int qi = 0; qi < 2; ++qi) {
        int u = qi * 256 + t;
        int l = u & 63;
        int row = ((u >> 6) << 4) + (l >> 2);
        int cblk = (l & 3) ^ (row & 3);
        const unsigned short* g = src + (size_t)(base_row + row) * Kp + k0 + cblk * 8;
        gl_lds16(g, lds + u * 8);
    }
}

// ---------------- 3-split 6-product MFMA GEMM, fp32 out: P = doc @ [W_s|W_e|W_a] ---------
__global__ __launch_bounds__(256, 2) void gemm6p(
    const unsigned short* __restrict__ A0, const unsigned short* __restrict__ A1,
    const unsigned short* __restrict__ A2,
    const unsigned short* __restrict__ B0, const unsigned short* __restrict__ B1,
    const unsigned short* __restrict__ B2,
    float* __restrict__ C) {
    __shared__ unsigned short As0[128 * 32], As1[128 * 32], As2[128 * 32];
    __shared__ unsigned short Bs0[128 * 32], Bs1[128 * 32], Bs2[128 * 32];
    int t = threadIdx.x;
    int bid = blockIdx.x;
    int bm = (bid & 15) << 7;
    int bn = (bid >> 4) << 7;
    int lane = t & 63, wv = t >> 6;
    int wm = (wv >> 1) * 64, wn = (wv & 1) * 64;
    int lr = lane & 15, qq = lane >> 4;
    int sw = (qq ^ (lr & 3)) * 8;

    f32x4 acc[4][4] = {};

    for (int k0 = 0; k0 < HIDDEN; k0 += 32) {
        stage_tile(A0, As0, bm, HIDDEN, k0, t);
        stage_tile(A1, As1, bm, HIDDEN, k0, t);
        stage_tile(A2, As2, bm, HIDDEN, k0, t);
        stage_tile(B0, Bs0, bn, HIDDEN, k0, t);
        stage_tile(B1, Bs1, bn, HIDDEN, k0, t);
        stage_tile(B2, Bs2, bn, HIDDEN, k0, t);
        __syncthreads();
        short8 a0[4], a1[4], a2[4];
#pragma unroll
        for (int i = 0; i < 4; ++i) {
            int ra = (wm + i * 16 + lr) * 32 + sw;
            a0[i] = *(const short8*)&As0[ra];
            a1[i] = *(const short8*)&As1[ra];
            a2[i] = *(const short8*)&As2[ra];
        }
#pragma unroll
        for (int j = 0; j < 4; ++j) {
            int rb = (wn + j * 16 + lr) * 32 + sw;
            short8 b0 = *(const short8*)&Bs0[rb];
            short8 b1 = *(const short8*)&Bs1[rb];
            short8 b2 = *(const short8*)&Bs2[rb];
#pragma unroll
            for (int i = 0; i < 4; ++i) {
                acc[i][j] = __builtin_amdgcn_mfma_f32_16x16x32_bf16(a2[i], b0, acc[i][j], 0, 0, 0);
                acc[i][j] = __builtin_amdgcn_mfma_f32_16x16x32_bf16(a0[i], b2, acc[i][j], 0, 0, 0);
                acc[i][j] = __builtin_amdgcn_mfma_f32_16x16x32_bf16(a1[i], b1, acc[i][j], 0, 0, 0);
                acc[i][j] = __builtin_amdgcn_mfma_f32_16x16x32_bf16(a1[i], b0, acc[i][j], 0, 0, 0);
                acc[i][j] = __builtin_amdgcn_mfma_f32_16x16x32_bf16(a0[i], b1, acc[i][j], 0, 0, 0);
                acc[i][j] = __builtin_amdgcn_mfma_f32_16x16x32_bf16(a0[i], b0, acc[i][j], 0, 0, 0);
            }
        }
        __syncthreads();
    }
#pragma unroll
    for (int i = 0; i < 4; ++i)
#pragma unroll
        for (int j = 0; j < 4; ++j)
#pragma unroll
            for (int r = 0; r < 4; ++r) {
                int m = bm + wm + i * 16 + qq * 4 + r;
                int n = bn + wn + j * 16 + lr;
                C[(size_t)m * PNP + n] = acc[i][j][r];
            }
}

// ---------------- combine: h1[c] = relu(P_s[s] + P_e[e] + sum attn*P_a[s+w] + Tw + b1) ----
__global__ void combine_kernel(const float* __restrict__ P, const float* __restrict__ tw,
                               const float* __restrict__ attn_g, const float* __restrict__ b1,
                               const int* __restrict__ starts, const int* __restrict__ ends,
                               unsigned short* __restrict__ h0, unsigned short* __restrict__ h1,
                               unsigned short* __restrict__ h2) {
    int c = blockIdx.x, t = threadIdx.x;
    int s = starts[c], e = ends[c];
    int wid = e - s;
    __shared__ float at[MSW];
    if (t < MSW) at[t] = attn_g[c * 32 + t];
    __syncthreads();
    const float* Ps = P + (size_t)s * PNP;
    const float* Pe = P + (size_t)e * PNP + 1024;
    const float* Pa = P + (size_t)s * PNP + 2048;
    const float* Tw = tw + (size_t)wid * NP;
    for (int n = t; n < NP; n += 256) {
        if (n < FFNN_DIM) {
            float acc = Ps[n] + Pe[n] + Tw[n] + b1[n];
            for (int w = 0; w <= wid; ++w) acc += at[w] * Pa[(size_t)w * PNP + n];
            store_split3(h0, h1, h2, (size_t)c * NP + n, fmaxf(acc, 0.f));
        } else {
            h0[(size_t)c * NP + n] = 0;
            h1[(size_t)c * NP + n] = 0;
            h2[(size_t)c * NP + n] = 0;
        }
    }
}

// ---------------- 3-split 6-product MFMA GEMM (score fusion) ------------
__global__ __launch_bounds__(256, 2) void gemm6(
    const unsigned short* __restrict__ A0, const unsigned short* __restrict__ A1,
    const unsigned short* __restrict__ A2,
    const unsigned short* __restrict__ B0, const unsigned short* __restrict__ B1,
    const unsigned short* __restrict__ B2,
    const float* __restrict__ bias, int nreal, int Kp,
    const float* __restrict__ w3, float* __restrict__ partials) {
    __shared__ unsigned short As0[128 * 32], As1[128 * 32], As2[128 * 32];
    __shared__ unsigned short Bs0[128 * 32], Bs1[128 * 32], Bs2[128 * 32];
    int t = threadIdx.x;
    int bid = blockIdx.x;
    int sm = bid >> 6, idx = bid & 63;
    int bm = ((sm << 3) + (idx & 7)) << 7;
    int bn = (idx >> 3) << 7;
    int lane = t & 63, wv = t >> 6;
    int wm = (wv >> 1) * 64, wn = (wv & 1) * 64;
    int lr = lane & 15, qq = lane >> 4;
    int sw = (qq ^ (lr & 3)) * 8;

    f32x4 acc[4][4] = {};

    for (int k0 = 0; k0 < Kp; k0 += 32) {
        stage_tile(A0, As0, bm, Kp, k0, t);
        stage_tile(A1, As1, bm, Kp, k0, t);
        stage_tile(A2, As2, bm, Kp, k0, t);
        stage_tile(B0, Bs0, bn, Kp, k0, t);
        stage_tile(B1, Bs1, bn, Kp, k0, t);
        stage_tile(B2, Bs2, bn, Kp, k0, t);
        __syncthreads();
        short8 a0[4], a1[4], a2[4];
#pragma unroll
        for (int i = 0; i < 4; ++i) {
            int ra = (wm + i * 16 + lr) * 32 + sw;
            a0[i] = *(const short8*)&As0[ra];
            a1[i] = *(const short8*)&As1[ra];
            a2[i] = *(const short8*)&As2[ra];
        }
#pragma unroll
        for (int j = 0; j < 4; ++j) {
            int rb = (wn + j * 16 + lr) * 32 + sw;
            short8 b0 = *(const short8*)&Bs0[rb];
            short8 b1 = *(const short8*)&Bs1[rb];
            short8 b2 = *(const short8*)&Bs2[rb];
#pragma unroll
            for (int i = 0; i < 4; ++i) {
                acc[i][j] = __builtin_amdgcn_mfma_f32_16x16x32_bf16(a2[i], b0, acc[i][j], 0, 0, 0);
                acc[i][j] = __builtin_amdgcn_mfma_f32_16x16x32_bf16(a0[i], b2, acc[i][j], 0, 0, 0);
                acc[i][j] = __builtin_amdgcn_mfma_f32_16x16x32_bf16(a1[i], b1, acc[i][j], 0, 0, 0);
                acc[i][j] = __builtin_amdgcn_mfma_f32_16x16x32_bf16(a1[i], b0, acc[i][j], 0, 0, 0);
                acc[i][j] = __builtin_amdgcn_mfma_f32_16x16x32_bf16(a0[i], b1, acc[i][j], 0, 0, 0);
                acc[i][j] = __builtin_amdgcn_mfma_f32_16x16x32_bf16(a0[i], b0, acc[i][j], 0, 0, 0);
            }
        }
        __syncthreads();
    }

    int pid = ((bn >> 7) << 1) | (wn >> 6);  // 0..15
#pragma unroll
    for (int i = 0; i < 4; ++i)
#pragma unroll
        for (int r = 0; r < 4; ++r) {
            float p = 0.f;
#pragma unroll
            for (int j = 0; j < 4; ++j) {
                int n = bn + wn + j * 16 + lr;
                float v = acc[i][j][r] + (n < nreal ? bias[n] : 0.f);
                v = fmaxf(v, 0.f);
                p += v * (n < nreal ? w3[n] : 0.f);
            }
            p += __shfl_xor(p, 1);
            p += __shfl_xor(p, 2);
            p += __shfl_xor(p, 4);
            p += __shfl_xor(p, 8);
            if (lr == 0) {
                int m = bm + wm + i * 16 + qq * 4 + r;
                partials[(size_t)m * 16 + pid] = p;
            }
        }
}

// ---------------- deterministic score finalize ----------------
__global__ void score_final(const float* __restrict__ partials, const float* __restrict__ b3,
                            const float* __restrict__ width_s, const int* __restrict__ starts,
                            const int* __restrict__ ends, float* __restrict__ out) {
    int c = blockIdx.x * 256 + threadIdx.x;
    if (c >= NUM_CAND) return;
    float s = b3[0] + width_s[ends[c] - starts[c]];
#pragma unroll
    for (int p = 0; p < 16; ++p) s += partials[(size_t)c * 16 + p];
    out[c] = s;
}

// ---------------- exact counting rank-sort: 256 blocks ----------------
__global__ __launch_bounds__(256) void rank_kernel(const float* __restrict__ scores,
                                                   const int* __restrict__ starts,
                                                   const int* __restrict__ ends,
                                                   unsigned short* __restrict__ ord_g,
                                                   unsigned int* __restrict__ se_g) {
    __shared__ unsigned long long kk[NUM_CAND];  // 64 KB
    int t = threadIdx.x;
    for (int i = t; i < NUM_CAND; i += 256) {
        unsigned int b = __float_as_uint(scores[i]);
        unsigned int u = b ^ ((b & 0x80000000u) ? 0xFFFFFFFFu : 0x80000000u);
        unsigned int hi = ~u;
        kk[i] = ((unsigned long long)hi << 32) | (unsigned int)i;
    }
    __syncthreads();
    int c = blockIdx.x * 32 + (t >> 3);
    int seg = (t & 7) * 1024;
    unsigned long long mykey = kk[c];
    int cnt = 0;
    for (int i = seg; i < seg + 1024; ++i) cnt += (kk[i] < mykey) ? 1 : 0;
    cnt += __shfl_xor(cnt, 1);
    cnt += __shfl_xor(cnt, 2);
    cnt += __shfl_xor(cnt, 4);
    if ((t & 7) == 0) {
        int idx = (int)(mykey & 0xFFFFFFFFull);
        int rank = cnt;
        ord_g[rank] = (unsigned short)idx;
        se_g[rank] = ((unsigned int)starts[idx] << 16) | (unsigned int)ends[idx];
    }
}

// ---------------- multi-wave pipelined greedy crossing-NMS ----------------
// 8 waves, r13 structure. r14 fix: amdgpu_waves_per_eu(1,2) lifts the VGPR cap to 256/wave
// (r13's VGPR_Count=40 spilled/serialized the 60-VGPR v[] batch — same failure as r7).
// Decision logic byte-identical to the r2..r13-verified form.
__global__ __launch_bounds__(512)
__attribute__((amdgpu_waves_per_eu(1, 2)))
void select_nms(const unsigned int* __restrict__ se_g,
                unsigned short* __restrict__ sel_g,
                int* __restrict__ count_g) {
    __shared__ unsigned int se_arr[NUM_CAND];   // 32 KB
    __shared__ unsigned int st[2 * NUM_WORDS];  // 16 KB
    __shared__ unsigned int lst[512];           //  2 KB accepts this round
    __shared__ int pos[9];                      // per-chunk accept-list offsets
    __shared__ int count_sh;
    int t = threadIdx.x;
    int wv = t >> 6, lane = t & 63;

    for (int i = t; i < NUM_CAND; i += 512) se_arr[i] = se_g[i];
    for (int i = t; i < 2 * NUM_WORDS; i += 512)
        st[i] = (i & 1) ? (unsigned int)NUM_WORDS : 0u;  // max_end+1=0, min_start=2048
    if (t == 0) count_sh = 0;
    __syncthreads();

    const unsigned long long* stp = (const unsigned long long*)st;
    for (int r = 0; r < NUM_CAND / 512; ++r) {
        int ib = r * 512 + wv * 64;  // this wave's chunk base rank
        unsigned int sev = se_arr[ib + lane];
        int s = (int)(sev >> 16), e = (int)(sev & 0xFFFFu);
        const unsigned long long* bp = stp + s;
        unsigned long long v[MSW];
#pragma unroll
        for (int w = 0; w < MSW; ++w) v[w] = bp[w];
        int me = (int)(unsigned int)v[0] - 1;
        bool crossed = (s < e) && ((int)(unsigned int)(v[0] >> 32) < s);
#pragma unroll
        for (int w = 1; w < MSW; ++w) {
            int j = s + w;
            bool in = (j <= e);
            int mej = (int)(unsigned int)v[w] - 1;
            int msj = (int)(unsigned int)(v[w] >> 32);
            crossed = crossed || (in && ((mej > e) || ((j < e) && (msj < s))));
        }
        bool spec = !crossed && (me != e);
        if (t == 0) pos[0] = 0;
        __syncthreads();

        for (int p = 0; p < 8; ++p) {
            if (p > 0 && wv >= p) {
                // apply fix-ups for chunk p-1's accepts (ranks strictly earlier than ours)
                int lo = pos[p - 1], hi = pos[p];
                for (int k = lo; k < hi; ++k) {
                    unsigned int sef = lst[k];
                    int sf = (int)(sef >> 16), ef = (int)(sef & 0xFFFFu);
                    if (s == sf) me = max(me, ef);
                    crossed = crossed || ((s < sf) && (sf <= e) && (ef > e))
                                      || ((sf < s) && (s <= ef) && (ef < e));
                }
                spec = !crossed && (me != e);
            }
            if (wv == p) {
                int cbefore = count_sh;
                int lbase = pos[p];
                if (cbefore < TOP_NUM) {
                    int count = cbefore;
                    unsigned long long window = ~0ull;
                    unsigned int pend = 0u;
                    int rk = 0, lcnt = 0;
                    while (true) {
                        unsigned long long b = __ballot(spec) & window;
                        if (b == 0ull) break;
                        int f = __ffsll((unsigned long long)b) - 1;
                        unsigned int sef = __builtin_amdgcn_readlane(sev, (unsigned int)f);
                        int sf = (int)(sef >> 16), ef = (int)(sef & 0xFFFFu);
                        bool mine = (lane == lcnt);
                        pend = mine ? sef : pend;
                        rk = mine ? (ib + f) : rk;
                        lcnt++;
                        count++;
                        if (count >= TOP_NUM) break;
                        window &= (f >= 63) ? 0ull : (~0ull << (f + 1));
                        if (lane > f) {
                            if (s == sf) me = max(me, ef);
                            crossed = crossed || ((s < sf) && (sf <= e) && (ef > e))
                                              || ((sf < s) && (s <= ef) && (ef < e));
                            spec = !crossed && (me != e);
                        }
                    }
                    if (lane < lcnt) {
                        int sf = (int)(pend >> 16), ef = (int)(pend & 0xFFFFu);
                        sel_g[cbefore + lane] = (unsigned short)rk;
                        lst[lbase + lane] = pend;
                        atomicMax(&st[2 * sf], (unsigned int)(ef + 1));
                        atomicMin(&st[2 * ef + 1], (unsigned int)sf);
                    }
                    if (lane == 0) {
                        count_sh = count;
                        pos[p + 1] = lbase + lcnt;
                    }
                } else {
                    if (lane == 0) pos[p + 1] = lbase;
                }
            }
            __syncthreads();
        }
        if (count_sh >= TOP_NUM) break;
    }
    if (t == 0) *count_g = count_sh;
}

// ---------------- post: final span-order sort + emit ----------------
__global__ __launch_bounds__(256) void select_post(const float* __restrict__ scores,
                                                   const int* __restrict__ starts,
                                                   const int* __restrict__ ends,
                                                   const unsigned short* __restrict__ ord_g,
                                                   const unsigned short* __restrict__ sel_g,
                                                   const int* __restrict__ count_g,
                                                   float* out, int* top_idx_ws) {
    __shared__ unsigned long long fkeys[1024];
    int t = threadIdx.x;
    int count = *count_g;
    for (int i = t; i < 1024; i += 256) {
        unsigned long long k = 0xFFFFFFFFFFFFFFFFull;
        if (i < count) {
            int idx = (int)ord_g[sel_g[i]];
            unsigned int key32 = (unsigned int)(starts[idx] * NUM_WORDS + ends[idx]);
            k = ((unsigned long long)key32 << 32) | (unsigned int)idx;
        }
        fkeys[i] = k;
    }
    __syncthreads();
    for (int size = 2; size <= 1024; size <<= 1) {
        for (int stride = size >> 1; stride > 0; stride >>= 1) {
            for (int i = t; i < 1024; i += 256) {
                int ixj = i ^ stride;
                if (ixj > i) {
                    bool up = ((i & size) == 0);
                    unsigned long long a = fkeys[i], b = fkeys[ixj];
                    if ((a > b) == up) { fkeys[i] = b; fkeys[ixj] = a; }
                }
            }
            __syncthreads();
        }
    }
    for (int i = t; i < TOP_NUM; i += 256) {
        int fi = (i < count) ? (int)(fkeys[i] & 0xFFFFFFFFull)
                             : (int)(fkeys[0] & 0xFFFFFFFFull);
        out[OUT_TOPIDX + i] = (float)fi;
        out[OUT_TSTART + i] = (float)starts[fi];
        out[OUT_TEND + i] = (float)ends[fi];
        out[OUT_TSCORE + i] = scores[fi];
        top_idx_ws[i] = fi;
    }
}

// ---------------- gather top_span_emb rows directly from doc (exact fp32) ----------------
__global__ void gather_emb(const float* __restrict__ doc, const float* __restrict__ swe,
                           const float* __restrict__ attn_g, const int* __restrict__ starts,
                           const int* __restrict__ ends, const int* __restrict__ top_idx_ws,
                           float* __restrict__ out) {
    int r = blockIdx.x, t = threadIdx.x;
    int idx = top_idx_ws[r];
    int s = starts[idx], e = ends[idx];
    int wid = e - s;
    __shared__ float at[MSW];
    if (t < MSW) at[t] = attn_g[(size_t)idx * 32 + t];
    __syncthreads();
    float* dst = out + OUT_TEMB + (size_t)r * SPAN_DIM;
    for (int h = t; h < HIDDEN; h += 256) {
        dst[h] = doc[(size_t)s * HIDDEN + h];
        dst[HIDDEN + h] = doc[(size_t)e * HIDDEN + h];
        float acc = 0.f;
        for (int w = 0; w <= wid; ++w) acc += at[w] * doc[(size_t)(s + w) * HIDDEN + h];
        dst[2 * HIDDEN + FEAT + h] = acc;
    }
    if (t < FEAT) dst[2 * HIDDEN + t] = swe[wid * FEAT + t];
}

extern "C" void kernel_launch(void* const* d_in, const int* in_sizes, int n_in,
                              void* d_out, int out_size, void* d_ws, size_t ws_size,
                              hipStream_t stream) {
    const float* mention_doc = (const float*)d_in[0];
    const float* span_width_emb = (const float*)d_in[1];
    const float* head_w = (const float*)d_in[2];
    const float* head_b = (const float*)d_in[3];
    const float* m_w1 = (const float*)d_in[4];
    const float* m_b1 = (const float*)d_in[5];
    const float* m_w2 = (const float*)d_in[6];
    const float* m_b2 = (const float*)d_in[7];
    const float* m_w3 = (const float*)d_in[8];
    const float* m_b3 = (const float*)d_in[9];
    const float* width_prior_emb = (const float*)d_in[10];
    const float* w_w1 = (const float*)d_in[11];
    const float* w_b1 = (const float*)d_in[12];
    const float* w_w2 = (const float*)d_in[13];
    const float* w_b2 = (const float*)d_in[14];
    const float* w_w3 = (const float*)d_in[15];
    const float* w_b3 = (const float*)d_in[16];
    const int* cand_starts = (const int*)d_in[17];
    const int* cand_ends = (const int*)d_in[18];

    char* w = (char*)d_ws;
    const size_t szH = (size_t)NUM_CAND * NP * 2;
    const size_t szW2 = (size_t)NP * KP2 * 2;
    const size_t szWc = (size_t)PNP * HIDDEN * 2;
    const size_t szD = (size_t)NUM_WORDS * HIDDEN * 2;
    char* p = w;
    unsigned short* h0 = (unsigned short*)p; p += szH;
    unsigned short* h1 = (unsigned short*)p; p += szH;
    unsigned short* h2 = (unsigned short*)p; p += szH;
    unsigned short* w2t0 = (unsigned short*)p; p += szW2;
    unsigned short* w2t1 = (unsigned short*)p; p += szW2;
    unsigned short* w2t2 = (unsigned short*)p; p += szW2;
    unsigned short* Wc0 = (unsigned short*)p; p += szWc;
    unsigned short* Wc1 = (unsigned short*)p; p += szWc;
    unsigned short* Wc2 = (unsigned short*)p; p += szWc;
    unsigned short* d0 = (unsigned short*)p; p += szD;
    unsigned short* d1 = (unsigned short*)p; p += szD;
    unsigned short* d2 = (unsigned short*)p; p += szD;
    float* P = (float*)p; p += (size_t)NUM_WORDS * PNP * 4;
    float* tw = (float*)p; p += (size_t)MSW * NP * 4;
    float* attn_g = (float*)p; p += (size_t)NUM_CAND * 32 * 4;
    float* partials = (float*)p; p += (size_t)NUM_CAND * 16 * 4;
    unsigned short* ord_g = (unsigned short*)p; p += (size_t)NUM_CAND * 2;
    unsigned int* se_g = (unsigned int*)p; p += (size_t)NUM_CAND * 4;
    unsigned short* sel_g = (unsigned short*)p; p += 2048;
    int* count_g = (int*)p; p += 128;
    float* head_s = (float*)p; p += NUM_WORDS * 4;
    float* width_s = (float*)p; p += 128;
    int* top_idx_ws = (int*)p; p += 4096;

    size_t need = (size_t)(p - w);
    if (ws_size < need) {
        fprintf(stderr, "kernel_launch: ws too small (%zu < %zu)\n", ws_size, need);
    }

    float* out = (float*)d_out;

    head_kernel<<<NUM_WORDS / 4, 256, 0, stream>>>(mention_doc, head_w, head_b, head_s);
    width_kernel<<<MSW, 256, 0, stream>>>(width_prior_emb, w_w1, w_b1, w_w2, w_b2, w_w3, w_b3,
                                          width_s);
    attn_kernel<<<NUM_CAND / 4, 256, 0, stream>>>(head_s, cand_starts, cand_ends, attn_g);
    doc_convert<<<(NUM_WORDS * HIDDEN + 255) / 256, 256, 0, stream>>>(mention_doc, d0, d1, d2);
    convert_wt<<<dim3(3, 1024), 256, 0, stream>>>(m_w1, HIDDEN, FFNN_DIM, HIDDEN,
                                                  Wc0, Wc1, Wc2);
    convert_wt<<<dim3(3, 1024), 256, 0, stream>>>(m_w1 + (size_t)HIDDEN * FFNN_DIM, HIDDEN,
                                                  FFNN_DIM, HIDDEN,
                                                  Wc0 + (size_t)1024 * HIDDEN,
                                                  Wc1 + (size_t)1024 * HIDDEN,
                                                  Wc2 + (size_t)1024 * HIDDEN);
    convert_wt<<<dim3(3, 1024), 256, 0, stream>>>(m_w1 + (size_t)1556 * FFNN_DIM, HIDDEN,
                                                  FFNN_DIM, HIDDEN,
                                                  Wc0 + (size_t)2048 * HIDDEN,
                                                  Wc1 + (size_t)2048 * HIDDEN,
                                                  Wc2 + (size_t)2048 * HIDDEN);
    convert_wt<<<dim3(4, 1024), 256, 0, stream>>>(m_w2, FFNN_DIM, FFNN_DIM, KP2,
                                                  w2t0, w2t1, w2t2);
    tw_kernel<<<MSW, 256, 0, stream>>>(span_width_emb, m_w1, tw);
    gemm6p<<<16 * 24, 256, 0, stream>>>(d0, d1, d2, Wc0, Wc1, Wc2, P);
    combine_kernel<<<NUM_CAND, 256, 0, stream>>>(P, tw, attn_g, m_b1, cand_starts, cand_ends,
                                                 h0, h1, h2);
    gemm6<<<512, 256, 0, stream>>>(h0, h1, h2, w2t0, w2t1, w2t2, m_b2, FFNN_DIM, KP2,
                                   m_w3, partials);
    score_final<<<NUM_CAND / 256, 256, 0, stream>>>(partials, m_b3, width_s, cand_starts,
                                                    cand_ends, out);
    rank_kernel<<<NUM_CAND / 32, 256, 0, stream>>>(out, cand_starts, cand_ends, ord_g, se_g);
    select_nms<<<1, 512, 0, stream>>>(se_g, sel_g, count_g);
    select_post<<<1, 256, 0, stream>>>(out, cand_starts, cand_ends, ord_g, sel_g, count_g,
                                       out, top_idx_ws);
    gather_emb<<<TOP_NUM, 256, 0, stream>>>(mention_doc, span_width_emb, attn_g, cand_starts,
                                            cand_ends, top_idx_ws, out);
}